// Round 6
// baseline (1648.719 us; speedup 1.0000x reference)
//
#include <hip/hip_runtime.h>
#include <hip/hip_bf16.h>
#include <stdint.h>

typedef __attribute__((ext_vector_type(8))) short short8;
typedef __attribute__((ext_vector_type(4))) float f32x4;
typedef unsigned short u16;

#define MFMA16(a,b,c) __builtin_amdgcn_mfma_f32_16x16x32_bf16((a),(b),(c),0,0,0)

__device__ __forceinline__ u16 f2bf(float f) {           // RNE f32->bf16
  unsigned int u = __float_as_uint(f);
  return (u16)((u + 0x7FFFu + ((u >> 16) & 1u)) >> 16);
}
__device__ __forceinline__ float bf2f(u16 h) {
  return __uint_as_float(((unsigned int)h) << 16);
}
__device__ __forceinline__ float clampf(float v, float lo, float hi) {
  return fminf(fmaxf(v, lo), hi);
}
__device__ __forceinline__ void gl2lds16(const u16* g, u16* l) {
  __builtin_amdgcn_global_load_lds(
      (const __attribute__((address_space(1))) unsigned int*)g,
      (__attribute__((address_space(3))) unsigned int*)(uintptr_t)l,
      16, 0, 0);
}

// ---------------------------------------------------------------- convert
__global__ __launch_bounds__(256) void cvt_bf16_kernel(
    const float* __restrict__ src, u16* __restrict__ dst, int n) {
  for (int i = blockIdx.x*256 + threadIdx.x; i < n; i += gridDim.x*256)
    dst[i] = f2bf(src[i]);
}

// ---------------------------------------------------------------- embed
__global__ __launch_bounds__(256) void embed_kernel(
    const int* __restrict__ iseq, const float* __restrict__ emb,
    u16* __restrict__ xb) {
  int gid = blockIdx.x*256 + threadIdx.x;
  int m = gid >> 7;
  int c = (gid & 127) * 4;
  int item = iseq[m];
  float4 e = *(const float4*)&emb[(size_t)item*512 + c];
  ushort4 hb;
  hb.x = f2bf(clampf(e.x*0.5f, -1.f, 1.f));
  hb.y = f2bf(clampf(e.y*0.5f, -1.f, 1.f));
  hb.z = f2bf(clampf(e.z*0.5f, -1.f, 1.f));
  hb.w = f2bf(clampf(e.w*0.5f, -1.f, 1.f));
  *(ushort4*)&xb[(size_t)m*512 + c] = hb;
}

// ---------------------------------------------------------------- valid count per batch
__global__ __launch_bounds__(256) void cnt_kernel(
    const int* __restrict__ item_seq, float* __restrict__ cnt) {
  __shared__ int sred[4];
  int b = blockIdx.x, tid = threadIdx.x;
  int lane = tid & 63, wv = tid >> 6;
  int c = 0;
  if (tid < 200) c = (item_seq[b*200 + tid] != 0) ? 1 : 0;
  #pragma unroll
  for (int m = 1; m <= 32; m <<= 1) c += __shfl_xor(c, m);
  if (lane == 0) sred[wv] = c;
  __syncthreads();
  if (tid == 0) cnt[b] = (float)(sred[0]+sred[1]+sred[2]+sred[3]);
}

// ---------------------------------------------------------------- GEMM  C = A @ W^T
// 256x256 tile, BK=64, 8 waves (2M x 4N). NEW structure for L2-resident
// weights: B-fragments loaded DIRECTLY from global (L2-hit) into registers,
// double-buffered one K-tile ahead (parity-unrolled, static regs). A stays
// in XOR-swizzled LDS, 64 KiB double-buffer -> LDS 68 KiB -> 2 blocks/CU
// (16 waves): cross-block MFMA/LDS overlap. 2 phases per K-tile:
//   ph1: load B(t+1)->regs ; rd A(t).h0 ; stage A(t+1).h1 ; BAR ; lgkm0 ;
//        32 MFMA (h0 x all 4 nf) ; vmcnt(12|0) ; BAR
//   ph2: rd A(t).h1 ; stage A(t+2).h0 ; BAR ; lgkm0 ;
//        32 MFMA (h1) ; vmcnt(12|10) ; BAR
// WAR slots: A(t+1).h1 overwrites A(t-1).h1 (reads done ph2(t-1)); A(t+2).h0
// overwrites A(t).h0 (reads done ph1(t)) — both separated by barriers.
// vmcnt ledger (B-loads + A-stages share vmcnt), newer-than-required = 12
// steady-state; tail peels 12 -> 10 -> 0. MODE 0: QKV scatter; 1: out_proj;
// 2: lin1+relu; 3: lin2.
#define BAR() asm volatile("s_barrier" ::: "memory")
#define LGKM0() do { asm volatile("s_waitcnt lgkmcnt(0)" ::: "memory"); \
                     __builtin_amdgcn_sched_barrier(0); } while (0)
#define VMW(N) asm volatile("s_waitcnt vmcnt(" #N ")" ::: "memory")

// Stage one half-tile (128 rows x 64 cols bf16 = 16 KiB) linearly into LDS,
// with the global SOURCE pre-swizzled so that LDS physical layout matches
// the XOR-swizzled read path (rule #21: both-sides-or-neither).
__device__ __forceinline__ void stage_half(const char* gsrc0, size_t rstride,
                                           u16* lhalf, int wv, int lane) {
  #pragma unroll
  for (int j = 0; j < 2; ++j) {
    const int o   = j*8192 + wv*1024 + lane*16;   // dest byte offset (linear)
    const int row = o >> 7;                        // 128 B per row
    const int cb  = (o & 127) ^ ((row & 7) << 4);  // inverse-swizzled src col
    gl2lds16((const u16*)(gsrc0 + (size_t)row*rstride + cb),
             (u16*)((char*)lhalf + j*8192 + wv*1024));
  }
}

// Swizzled ds_read_b128 of one MFMA fragment. kb = byte col (mult of 16).
__device__ __forceinline__ short8 ldsfrag(const u16* slot, int row, int kb) {
  return *(const short8*)((const char*)slot + row*128 + (kb ^ ((row & 7) << 4)));
}

template <int MODE>
__global__ __launch_bounds__(512, 2)
void gemm_bt(const u16* __restrict__ A, const u16* __restrict__ Bw,
             const float* __restrict__ bias, int K, int Nt, int swz,
             u16* __restrict__ outB, u16* __restrict__ QKV, long long projStride) {
  __shared__ __align__(16) u16 SH[34816];       // 68 KiB (A dbuf 64K; epi 68K)
  u16* const As0 = SH;                          // 32 KiB each
  u16* const As1 = SH + 16384;
  const int tid  = threadIdx.x;
  const int lane = tid & 63;
  const int wv   = tid >> 6;          // 0..7
  const int wm   = wv >> 2;           // 0..1  (128-row half)
  const int wn   = wv & 3;            // 0..3  (64-col strip)
  const int id   = blockIdx.x;
  int mt, nt2;
  if (swz) { mt = (id / (8*Nt))*8 + (id & 7); nt2 = (id >> 3) % Nt; }
  else     { mt = id / Nt;                    nt2 = id % Nt; }
  const int m0 = mt * 256;
  const int n0 = nt2 * 256;
  const int KT = K >> 6;              // K-tiles of 64 (8 or 16, even)

  const char* Abase = (const char*)(A  + (size_t)m0*K);
  const char* Bbase = (const char*)(Bw + (size_t)n0*K);
  const size_t rs = (size_t)K * 2;

  const int r16 = lane & 15;
  const int q4  = lane >> 4;
  const size_t browB = (size_t)(wn*64 + r16)*rs + q4*16;  // lane's B row base

  const f32x4 fz = {0.f, 0.f, 0.f, 0.f};
  f32x4 acc[8][4];
  #pragma unroll
  for (int i = 0; i < 8; ++i)
    #pragma unroll
    for (int j = 0; j < 4; ++j) acc[i][j] = fz;

  short8 af[4][2];
  short8 bfA[4][2], bfB[4][2];

  // ---- prologue: B(0)->bfA ; stage A0.h0, A0.h1, A1.h0 ; retire A0 ; BAR
  #pragma unroll
  for (int nf = 0; nf < 4; ++nf)
    #pragma unroll
    for (int ks = 0; ks < 2; ++ks)
      bfA[nf][ks] = *(const short8*)(Bbase + browB + (size_t)nf*16*rs + ks*64);
  stage_half(Abase,              rs, As0,            wv, lane);
  stage_half(Abase + 128*rs,     rs, As0 + 128*64,   wv, lane);
  stage_half(Abase + 128,        rs, As1,            wv, lane);
  VMW(2);                         // retires A0.h0+h1 (A1.h0 may fly)
  BAR();

  // one K-step (two phases); parity-static buffers/registers
  auto kstep = [&](int t, u16* Acur, u16* Aoth,
                   short8 (&bfC)[4][2], short8 (&bfN)[4][2]) {
    const bool l1 = (t + 1 < KT);
    const bool l2 = (t + 2 < KT);
    const char* Bg1 = Bbase + (size_t)(t+1)*128;
    const char* Ag1 = Abase + (size_t)(t+1)*128;
    const char* Ag2 = Abase + (size_t)(t+2)*128;
    // ---- ph1: B(t+1)->bfN ; rd A(t).h0 ; stage A(t+1).h1 ; MFMA h0
    if (l1) {
      #pragma unroll
      for (int nf = 0; nf < 4; ++nf)
        #pragma unroll
        for (int ks = 0; ks < 2; ++ks)
          bfN[nf][ks] = *(const short8*)(Bg1 + browB + (size_t)nf*16*rs + ks*64);
    }
    #pragma unroll
    for (int i = 0; i < 4; ++i)
      #pragma unroll
      for (int ks = 0; ks < 2; ++ks)
        af[i][ks] = ldsfrag(Acur, wm*128 + i*16 + r16, ks*64 + q4*16);
    if (l1) stage_half(Ag1 + 128*rs, rs, Aoth + 128*64, wv, lane);
    BAR(); LGKM0();
    __builtin_amdgcn_s_setprio(1);
    #pragma unroll
    for (int i = 0; i < 4; ++i)
      #pragma unroll
      for (int nf = 0; nf < 4; ++nf)
        #pragma unroll
        for (int ks = 0; ks < 2; ++ks)
          acc[i][nf] = MFMA16(af[i][ks], bfC[nf][ks], acc[i][nf]);
    __builtin_amdgcn_s_setprio(0);
    if (l1) { VMW(12); } else { VMW(0); }
    BAR();
    // ---- ph2: rd A(t).h1 ; stage A(t+2).h0 ; MFMA h1
    #pragma unroll
    for (int i = 0; i < 4; ++i)
      #pragma unroll
      for (int ks = 0; ks < 2; ++ks)
        af[i][ks] = ldsfrag(Acur, wm*128 + 64 + i*16 + r16, ks*64 + q4*16);
    if (l2) stage_half(Ag2, rs, Acur, wv, lane);
    BAR(); LGKM0();
    __builtin_amdgcn_s_setprio(1);
    #pragma unroll
    for (int i = 0; i < 4; ++i)
      #pragma unroll
      for (int nf = 0; nf < 4; ++nf)
        #pragma unroll
        for (int ks = 0; ks < 2; ++ks)
          acc[4+i][nf] = MFMA16(af[i][ks], bfC[nf][ks], acc[4+i][nf]);
    __builtin_amdgcn_s_setprio(0);
    if (l2) { VMW(12); } else if (l1) { VMW(10); }
    BAR();
  };

  const int NI = KT >> 1;
  for (int it = 0; it < NI; ++it) {
    kstep(it*2,     As0, As1, bfA, bfB);
    kstep(it*2 + 1, As1, As0, bfB, bfA);
  }

  // ---- epilogue: LDS-retranspose coalesced stores (round-5 structure) ----
  {
    u16* const L = SH;
    const int LROW = 272;
    #pragma unroll
    for (int h = 0; h < 2; ++h) {
      if (h == 1) __syncthreads();               // protect L reuse across passes
      if (wm == h) {
        #pragma unroll
        for (int nf = 0; nf < 4; ++nf) {
          const int col_l = wn*64 + nf*16 + r16;
          const float bvs = (MODE == 0) ? 0.f : bias[n0 + col_l];
          #pragma unroll
          for (int mi = 0; mi < 8; ++mi) {
            const int row_l = mi*16 + q4*4;
            #pragma unroll
            for (int r = 0; r < 4; ++r) {
              float v = acc[mi][nf][r];
              if (MODE == 0)      v = clampf(v, -1.f, 1.f);
              else if (MODE == 1) v = clampf(v + bvs, -3.f, 3.f);
              else if (MODE == 2) v = fmaxf(clampf(v + bvs, -2.f, 2.f), 0.f);
              else                v = clampf(v + bvs, -2.f, 2.f);
              L[(row_l + r)*LROW + col_l] = f2bf(v);
            }
          }
        }
      }
      __syncthreads();
      #pragma unroll
      for (int k = 0; k < 8; ++k) {
        const int ch   = wv*512 + k*64 + lane;   // 16B chunk id (0..4095)
        const int row  = ch >> 5;                // 32 chunks per 256-col row
        const int colu = (ch & 31) * 8;          // u16 col
        short8 d = *(const short8*)&L[row*LROW + colu];
        const int rowg = m0 + h*128 + row;
        const int cg   = n0 + colu;
        if (MODE == 0) {
          const unsigned proj = (unsigned)cg >> 9;
          const unsigned hh   = ((unsigned)cg >> 6) & 7u;
          const unsigned dk   = (unsigned)cg & 63u;
          const int b = rowg / 200;
          const int s = rowg - b*200;
          *(short8*)&QKV[(size_t)proj*projStride + (size_t)hh*12800
                         + (size_t)b*102400 + (size_t)s*64 + dk] = d;
        } else {
          const int N = (MODE == 2) ? 1024 : 512;
          *(short8*)&outB[(size_t)rowg*N + cg] = d;
        }
      }
    }
  }
}

// ---------------------------------------------------------------- fused attention
// 8 waves / 512 threads: 2 q-blocks of 128 rows. LDS ~70.7 KB -> 2 blocks/CU,
// 16 waves/CU. V-transpose staging conflict-free (lanes write consecutive s).
__global__ __launch_bounds__(512)
void attn_kernel(const u16* __restrict__ Q, const u16* __restrict__ K,
                 const u16* __restrict__ V, const int* __restrict__ iseq,
                 u16* __restrict__ x2b) {
  __shared__ __align__(16) u16 Ks[208*72];
  __shared__ __align__(16) u16 Vs[64*232];
  __shared__ __align__(16) u16 Ps[8][16*40];
  __shared__ float msk[208];

  const int tid = threadIdx.x, lane = tid & 63, wv = tid >> 6;
  const unsigned bid = blockIdx.x;
  const int h = bid & 7;
  const int b = bid >> 3;
  const size_t bh = (size_t)b*8 + h;
  const u16* Kg = K + bh*12800;
  const u16* Vg = V + bh*12800;
  const u16* Qg = Q + bh*12800;

  for (int c = tid; c < 3200; c += 512) {       // K -> Ks[key][dk]
    int row = c >> 4, q = c & 15;
    *(ushort4*)&Ks[row*72 + q*4] = *(const ushort4*)&Kg[row*64 + q*4];
  }
  // V -> Vs[dk][s] transpose: wave w owns d-quads {2w, 2w+1}; lanes walk
  // consecutive s -> contiguous u16 LDS stores (no bank conflicts).
  {
    const int quad = wv*2 + (lane >> 5);        // 0..15
    const int sl   = lane & 31;
    #pragma unroll
    for (int it = 0; it < 7; ++it) {
      const int s = sl + it*32;
      if (s < 200) {
        ushort4 v4 = *(const ushort4*)&Vg[s*64 + quad*4];
        Vs[(quad*4+0)*232 + s] = v4.x;
        Vs[(quad*4+1)*232 + s] = v4.y;
        Vs[(quad*4+2)*232 + s] = v4.z;
        Vs[(quad*4+3)*232 + s] = v4.w;
      }
    }
  }
  for (int c = tid; c < 2048; c += 512) {
    int dk = c >> 5, s2 = 200 + (c & 31);
    Vs[dk*232 + s2] = 0;
  }
  for (int t = tid; t < 208; t += 512)
    msk[t] = (t < 200 && iseq[b*200 + t] != 0) ? 1.f : 0.f;
  __syncthreads();

  const int colk = lane & 15;
  const int fk8 = (lane >> 4) * 8;
  const int prow = (lane >> 4) * 4;
  const f32x4 fz = {0.f,0.f,0.f,0.f};

  for (int qb = 0; qb < 2; ++qb) {
    const int qrow = qb*128 + wv*16 + (lane & 15);
    const int qsrc = qrow < 200 ? qrow : 199;
    short8 qa0 = *(const short8*)&Qg[(size_t)qsrc*64 + fk8];
    short8 qa1 = *(const short8*)&Qg[(size_t)qsrc*64 + 32 + fk8];
    f32x4 oacc[4];
    #pragma unroll
    for (int nt = 0; nt < 4; ++nt) oacc[nt] = fz;
    float rs[4] = {0.f,0.f,0.f,0.f};

    for (int kt2 = 0; kt2 < 7; ++kt2) {
      #pragma unroll
      for (int half = 0; half < 2; ++half) {
        const int stile = kt2*2 + half;
        if (stile < 13) {
          const int key = stile*16 + colk;
          short8 kb0 = *(const short8*)&Ks[key*72 + fk8];
          short8 kb1 = *(const short8*)&Ks[key*72 + 32 + fk8];
          f32x4 sc = fz;
          __builtin_amdgcn_s_setprio(1);
          sc = MFMA16(qa0, kb0, sc);
          sc = MFMA16(qa1, kb1, sc);
          __builtin_amdgcn_s_setprio(0);
          const float mk = msk[key];
          #pragma unroll
          for (int r = 0; r < 4; ++r) {
            float p = __expf(clampf(sc[r]*2.5f, -3.f, 3.f)) * mk;
            rs[r] += p;
            Ps[wv][(prow + r)*40 + half*16 + colk] = f2bf(p);
          }
        } else {
          #pragma unroll
          for (int r = 0; r < 4; ++r)
            Ps[wv][(prow + r)*40 + half*16 + colk] = 0;
        }
      }
      asm volatile("s_waitcnt lgkmcnt(0)" ::: "memory");
      short8 pa = *(const short8*)&Ps[wv][(lane & 15)*40 + fk8];
      const int kb32 = kt2*32;
      __builtin_amdgcn_s_setprio(1);
      #pragma unroll
      for (int nt = 0; nt < 4; ++nt) {
        short8 vb = *(const short8*)&Vs[(nt*16 + colk)*232 + kb32 + fk8];
        oacc[nt] = MFMA16(pa, vb, oacc[nt]);
      }
      __builtin_amdgcn_s_setprio(0);
      asm volatile("s_waitcnt lgkmcnt(0)" ::: "memory");
    }

    #pragma unroll
    for (int m = 1; m <= 8; m <<= 1)
      #pragma unroll
      for (int r = 0; r < 4; ++r) rs[r] += __shfl_xor(rs[r], m);

    const int srow = qb*128 + wv*16 + prow;
    #pragma unroll
    for (int r = 0; r < 4; ++r) {
      const int s = srow + r;
      if (s < 200) {
        const float inv = rs[r] > 0.f ? 1.f/rs[r] : 0.f;
        const size_t base = ((size_t)b*200 + s)*512 + h*64;
        #pragma unroll
        for (int nt = 0; nt < 4; ++nt)
          x2b[base + nt*16 + colk] = f2bf(oacc[nt][r] * inv);
      }
    }
  }
}

// ---------------------------------------------------------------- LN1 (double): xn = LN(x + LN(x+x2)); x from xb (bf16)
__global__ __launch_bounds__(256)
void ln1_kernel(const u16* __restrict__ xb, const u16* __restrict__ x2b,
                const float* __restrict__ g, const float* __restrict__ bb,
                u16* __restrict__ xnb) {
  const int lane = threadIdx.x & 63, wv = threadIdx.x >> 6;
  const size_t t = (size_t)blockIdx.x*4 + wv;
  const int c0 = lane*4, c1 = 256 + lane*4;
  ushort4 xa = *(const ushort4*)&xb[t*512 + c0];
  ushort4 xc = *(const ushort4*)&xb[t*512 + c1];
  ushort4 ha = *(const ushort4*)&x2b[t*512 + c0];
  ushort4 hc = *(const ushort4*)&x2b[t*512 + c1];
  float xv[8] = {bf2f(xa.x),bf2f(xa.y),bf2f(xa.z),bf2f(xa.w),
                 bf2f(xc.x),bf2f(xc.y),bf2f(xc.z),bf2f(xc.w)};
  float tv[8] = {xv[0]+bf2f(ha.x), xv[1]+bf2f(ha.y), xv[2]+bf2f(ha.z), xv[3]+bf2f(ha.w),
                 xv[4]+bf2f(hc.x), xv[5]+bf2f(hc.y), xv[6]+bf2f(hc.z), xv[7]+bf2f(hc.w)};
  float s1 = 0.f, s2 = 0.f;
  #pragma unroll
  for (int i = 0; i < 8; ++i) { s1 += tv[i]; s2 += tv[i]*tv[i]; }
  #pragma unroll
  for (int m = 1; m <= 32; m <<= 1) { s1 += __shfl_xor(s1, m); s2 += __shfl_xor(s2, m); }
  float mean = s1*(1.f/512.f);
  float inv = 1.f/sqrtf(s2*(1.f/512.f) - mean*mean + 1e-6f);
  float4 ga = *(const float4*)(g + c0), gc = *(const float4*)(g + c1);
  float4 ba = *(const float4*)(bb + c0), bc = *(const float4*)(bb + c1);
  float gv[8] = {ga.x,ga.y,ga.z,ga.w, gc.x,gc.y,gc.z,gc.w};
  float bv[8] = {ba.x,ba.y,ba.z,ba.w, bc.x,bc.y,bc.z,bc.w};
  float uv[8]; float s3 = 0.f, s4 = 0.f;
  #pragma unroll
  for (int i = 0; i < 8; ++i) {
    float sa = (tv[i]-mean)*inv*gv[i] + bv[i];
    uv[i] = xv[i] + sa;
    s3 += uv[i]; s4 += uv[i]*uv[i];
  }
  #pragma unroll
  for (int m = 1; m <= 32; m <<= 1) { s3 += __shfl_xor(s3, m); s4 += __shfl_xor(s4, m); }
  float mean2 = s3*(1.f/512.f);
  float inv2 = 1.f/sqrtf(s4*(1.f/512.f) - mean2*mean2 + 1e-6f);
  ushort4 o0, o1;
  o0.x = f2bf((uv[0]-mean2)*inv2*gv[0] + bv[0]);
  o0.y = f2bf((uv[1]-mean2)*inv2*gv[1] + bv[1]);
  o0.z = f2bf((uv[2]-mean2)*inv2*gv[2] + bv[2]);
  o0.w = f2bf((uv[3]-mean2)*inv2*gv[3] + bv[3]);
  o1.x = f2bf((uv[4]-mean2)*inv2*gv[4] + bv[4]);
  o1.y = f2bf((uv[5]-mean2)*inv2*gv[5] + bv[5]);
  o1.z = f2bf((uv[6]-mean2)*inv2*gv[6] + bv[6]);
  o1.w = f2bf((uv[7]-mean2)*inv2*gv[7] + bv[7]);
  *(ushort4*)&xnb[t*512 + c0] = o0;
  *(ushort4*)&xnb[t*512 + c1] = o1;
}

// ---------------------------------------------------------------- LN2 (double) + masked partials — barrier-free
__global__ __launch_bounds__(256)
void ln2_kernel(const u16* __restrict__ xnb, const u16* __restrict__ f2b,
                const float* __restrict__ g, const float* __restrict__ bb,
                const int* __restrict__ iseq, float* __restrict__ seq_acc) {
  const int tid = threadIdx.x, lane = tid & 63, wv = tid >> 6;
  const int q = blockIdx.x, bl = blockIdx.y;
  const int c8 = lane*8;
  float gv[8], bv[8];
  *(float4*)&gv[0] = *(const float4*)(g + c8);
  *(float4*)&gv[4] = *(const float4*)(g + c8 + 4);
  *(float4*)&bv[0] = *(const float4*)(bb + c8);
  *(float4*)&bv[4] = *(const float4*)(bb + c8 + 4);
  float acc[8] = {};
  for (int i = wv; i < 50; i += 4) {
    const int s = q*50 + i;
    const size_t row = (size_t)bl*200 + s;
    short8 xh = *(const short8*)&xnb[row*512 + c8];
    short8 yh = *(const short8*)&f2b[row*512 + c8];
    float xv[8], tv[8];
    #pragma unroll
    for (int j = 0; j < 8; ++j) {
      xv[j] = bf2f((u16)xh[j]);
      tv[j] = xv[j] + bf2f((u16)yh[j]);
    }
    float s1 = 0.f, s2 = 0.f;
    #pragma unroll
    for (int j = 0; j < 8; ++j) { s1 += tv[j]; s2 += tv[j]*tv[j]; }
    #pragma unroll
    for (int m = 1; m <= 32; m <<= 1) { s1 += __shfl_xor(s1,m); s2 += __shfl_xor(s2,m); }
    float mean = s1*(1.f/512.f);
    float inv = 1.f/sqrtf(s2*(1.f/512.f) - mean*mean + 1e-6f);
    float uv[8]; float s3 = 0.f, s4 = 0.f;
    #pragma unroll
    for (int j = 0; j < 8; ++j) {
      uv[j] = xv[j] + (tv[j]-mean)*inv*gv[j] + bv[j];
      s3 += uv[j]; s4 += uv[j]*uv[j];
    }
    #pragma unroll
    for (int m = 1; m <= 32; m <<= 1) { s3 += __shfl_xor(s3,m); s4 += __shfl_xor(s4,m); }
    float mean2 = s3*(1.f/512.f);
    float inv2 = 1.f/sqrtf(s4*(1.f/512.f) - mean2*mean2 + 1e-6f);
    if (iseq[row] != 0) {
      #pragma unroll
      for (int j = 0; j < 8; ++j)
        acc[j] += clampf((uv[j]-mean2)*inv2*gv[j] + bv[j], -5.f, 5.f);
    }
  }
  float* dst = &seq_acc[(((size_t)bl*4 + q)*4 + wv)*512 + c8];
  *(float4*)&dst[0] = *(float4*)&acc[0];
  *(float4*)&dst[4] = *(float4*)&acc[4];
}

// ---------------------------------------------------------------- assemble user vector u (512 x 1152)
__global__ __launch_bounds__(256)
void build_u_kernel(const float* __restrict__ seq_acc, const float* __restrict__ cnt,
                    const float* __restrict__ uac, const float* __restrict__ uti,
                    const int* __restrict__ age, const int* __restrict__ gen,
                    const int* __restrict__ cms,
                    const float* __restrict__ age_tab, const float* __restrict__ gen_tab,
                    const float* __restrict__ cms_tab,
                    const float* __restrict__ ctr_w, const float* __restrict__ ctr_b,
                    const float* __restrict__ ti_w, const float* __restrict__ ti_b,
                    float* __restrict__ u) {
  const int b = blockIdx.x;
  for (int j = threadIdx.x; j < 1152; j += 256) {
    float v;
    if (j < 512) {
      float ssum = 0.f;
      #pragma unroll
      for (int p = 0; p < 16; ++p) ssum += seq_acc[((size_t)b*16 + p)*512 + j];
      v = clampf(ssum / (cnt[b] + 1e-8f), -5.f, 5.f);
    }
    else if (j < 640)  { int e = j-512;  v = uac[b]*ctr_w[e] + ctr_b[e]; }
    else if (j < 768)  { int e = j-640;  v = uti[b]*ti_w[e] + ti_b[e]; }
    else if (j < 896)  { int e = j-768;  v = age_tab[age[b]*128 + e]; }
    else if (j < 1024) { int e = j-896;  v = gen_tab[gen[b]*128 + e]; }
    else               { int e = j-1024; v = cms_tab[cms[b]*128 + e]; }
    u[(size_t)b*1152 + j] = v;
  }
}

// ---------------------------------------------------------------- mlp1
__global__ __launch_bounds__(256)
void mlp1_kernel(const float* __restrict__ u, const float* __restrict__ w,
                 const float* __restrict__ bias, float* __restrict__ h1) {
  __shared__ __align__(16) float As[64][36];
  __shared__ __align__(16) float Wt[32][68];
  const int tid = threadIdx.x;
  const int m0 = blockIdx.x*64, n0 = blockIdx.y*64;
  const int tm = tid >> 4, tn = tid & 15;
  float acc[4][4] = {};
  for (int k0 = 0; k0 < 1152; k0 += 32) {
    for (int c = tid; c < 512; c += 256) {
      int row = c >> 3, q = c & 7;
      *(float4*)&As[row][q*4] = *(const float4*)&u[(size_t)(m0+row)*1152 + k0 + q*4];
      float4 wv4 = *(const float4*)&w[(size_t)(n0+row)*1152 + k0 + q*4];
      Wt[q*4+0][row] = wv4.x; Wt[q*4+1][row] = wv4.y;
      Wt[q*4+2][row] = wv4.z; Wt[q*4+3][row] = wv4.w;
    }
    __syncthreads();
    #pragma unroll
    for (int kk = 0; kk < 32; ++kk) {
      float av[4], bw[4];
      #pragma unroll
      for (int i = 0; i < 4; ++i) av[i] = As[tm*4+i][kk];
      #pragma unroll
      for (int j = 0; j < 4; ++j) bw[j] = Wt[kk][tn*4+j];
      #pragma unroll
      for (int i = 0; i < 4; ++i)
        #pragma unroll
        for (int j = 0; j < 4; ++j) acc[i][j] += av[i]*bw[j];
    }
    __syncthreads();
  }
  #pragma unroll
  for (int i = 0; i < 4; ++i)
    #pragma unroll
    for (int j = 0; j < 4; ++j) {
      int n = n0 + tn*4 + j;
      h1[(size_t)(m0 + tm*4 + i)*1024 + n] = fmaxf(acc[i][j] + bias[n], 0.f);
    }
}

// ---------------------------------------------------------------- mlp2
__global__ __launch_bounds__(256)
void mlp2_kernel(const float* __restrict__ h1, const float* __restrict__ w,
                 const float* __restrict__ bias, float* __restrict__ out) {
  const int tid = threadIdx.x;
  const int m = blockIdx.x*4 + (tid >> 6);
  const int n = tid & 63;
  const float4* hr = (const float4*)(h1 + (size_t)m*1024);
  const float4* wr = (const float4*)(w + (size_t)n*1024);
  float acc = 0.f;
  for (int k4 = 0; k4 < 256; ++k4) {
    float4 a = hr[k4], bw = wr[k4];
    acc += a.x*bw.x + a.y*bw.y + a.z*bw.z + a.w*bw.w;
  }
  out[(size_t)m*64 + n] = acc + bias[n];
}

// ================================================================ launch
extern "C" void kernel_launch(void* const* d_in, const int* in_sizes, int n_in,
                              void* d_out, int out_size, void* d_ws, size_t ws_size,
                              hipStream_t stream) {
  (void)in_sizes; (void)n_in; (void)out_size;
  const int*   item_seq   = (const int*)d_in[0];
  const float* uac        = (const float*)d_in[1];
  const float* uti        = (const float*)d_in[2];
  const int*   age        = (const int*)d_in[3];
  const int*   gen        = (const int*)d_in[4];
  const int*   cms        = (const int*)d_in[5];
  const float* emb        = (const float*)d_in[6];
  const float* in_proj_w  = (const float*)d_in[7];
  const float* out_proj_w = (const float*)d_in[8];
  const float* out_proj_b = (const float*)d_in[9];
  const float* ln1_g = (const float*)d_in[10];
  const float* ln1_b = (const float*)d_in[11];
  const float* ln2_g = (const float*)d_in[12];
  const float* ln2_b = (const float*)d_in[13];
  const float* lin1_w = (const float*)d_in[14];
  const float* lin1_b = (const float*)d_in[15];
  const float* lin2_w = (const float*)d_in[16];
  const float* lin2_b = (const float*)d_in[17];
  const float* age_tab = (const float*)d_in[18];
  const float* gen_tab = (const float*)d_in[19];
  const float* cms_tab = (const float*)d_in[20];
  const float* ctr_w = (const float*)d_in[21];
  const float* ctr_b = (const float*)d_in[22];
  const float* ti_w  = (const float*)d_in[23];
  const float* ti_b  = (const float*)d_in[24];
  const float* mlp1_w = (const float*)d_in[25];
  const float* mlp1_b = (const float*)d_in[26];
  const float* mlp2_w = (const float*)d_in[27];
  const float* mlp2_b = (const float*)d_in[28];

  // ---- adaptive chunking: 5 regions of CB*200*512*2 B each + tail ----
  const long long TAILB = 25430016LL;
  int CB = 32;
  if      ((long long)ws_size >= 512LL*1024000 + TAILB) CB = 512;  // 549.7 MB (ws ~819 MB)
  else if ((long long)ws_size >= 128LL*1024000 + TAILB) CB = 128;
  else if ((long long)ws_size >=  64LL*1024000 + TAILB) CB = 64;
  const long long R = (long long)CB * 204800;

  char* ws = (char*)d_ws;
  u16* xb   = (u16*)(ws);            // region 0: embed bf16 (live through ln1)
  u16* x2b  = (u16*)(ws + R);        // region 1: attn out
  u16* Qb   = (u16*)(ws + 2*R);      // region 2: Q; later x2o
  u16* Kb   = (u16*)(ws + 3*R);      // region 3: K; later xnb
  u16* Vrb  = (u16*)(ws + 4*R);      // region 4: V; later f2b
  u16* x2o  = Qb;
  u16* xnb  = Kb;
  u16* f2b  = Vrb;
  u16* hbuf = (u16*)(ws);            // regions 0-1 (xb,x2b dead after ln1)
  char* tail = ws + 5*R;
  float* seq_acc = (float*)(tail);              // 16,777,216  [B][16][512]
  float* cnt     = (float*)(tail + 16777216);   // 2,048
  float* u       = (float*)(tail + 16779264);   // 2,359,296
  float* h1      = (float*)(tail + 19138560);   // 2,097,152
  u16*   wqkv    = (u16*)(tail + 21235712);     // 1,572,864
  u16*   wout    = (u16*)(tail + 22808576);     // 524,288
  u16*   wl1     = (u16*)(tail + 23332864);     // 1,048,576
  u16*   wl2     = (u16*)(tail + 24381440);     // 1,048,576 -> 25,430,016

  cvt_bf16_kernel<<<768, 256, 0, stream>>>(in_proj_w, wqkv, 1536*512);
  cvt_bf16_kernel<<<256, 256, 0, stream>>>(out_proj_w, wout, 512*512);
  cvt_bf16_kernel<<<512, 256, 0, stream>>>(lin1_w, wl1, 1024*512);
  cvt_bf16_kernel<<<512, 256, 0, stream>>>(lin2_w, wl2, 512*1024);
  cnt_kernel<<<512, 256, 0, stream>>>(item_seq, cnt);

  const int nch = 512 / CB;
  const int Mc  = CB * 200;
  const int Mt  = Mc / 256;                    // 256-row tiles
  const int swz = (Mt % 8 == 0) ? 1 : 0;
  const long long projStride = (long long)CB * 102400;
  for (int ch = 0; ch < nch; ++ch) {
    const int* iseq = item_seq + (size_t)ch*CB*200;
    embed_kernel<<<Mc/2, 256, 0, stream>>>(iseq, emb, xb);
    gemm_bt<0><<<Mt*6, 512, 0, stream>>>(xb, wqkv, nullptr, 512, 6, swz,
                                         nullptr, Qb, projStride);
    attn_kernel<<<CB*8, 512, 0, stream>>>(Qb, Kb, Vrb, iseq, x2b);
    gemm_bt<1><<<Mt*2, 512, 0, stream>>>(x2b, wout, out_proj_b, 512, 2, swz,
                                         x2o, nullptr, 0);
    ln1_kernel<<<Mc/4, 256, 0, stream>>>(xb, x2o, ln1_g, ln1_b, xnb);
    gemm_bt<2><<<Mt*4, 512, 0, stream>>>(xnb, wl1, lin1_b, 512, 4, swz,
                                         hbuf, nullptr, 0);
    gemm_bt<3><<<Mt*2, 512, 0, stream>>>(hbuf, wl2, lin2_b, 1024, 2, swz,
                                         f2b, nullptr, 0);
    ln2_kernel<<<dim3(4, CB), 256, 0, stream>>>(xnb, f2b, ln2_g, ln2_b, iseq,
                                                seq_acc + (size_t)ch*CB*8192);
  }

  build_u_kernel<<<512, 256, 0, stream>>>(seq_acc, cnt, uac, uti, age, gen, cms,
                                          age_tab, gen_tab, cms_tab,
                                          ctr_w, ctr_b, ti_w, ti_b, u);
  mlp1_kernel<<<dim3(8, 16), 256, 0, stream>>>(u, mlp1_w, mlp1_b, h1);
  mlp2_kernel<<<128, 256, 0, stream>>>(h1, mlp2_w, mlp2_b, (float*)d_out);
}

// Round 7
// 1539.013 us; speedup vs baseline: 1.0713x; 1.0713x over previous
//
#include <hip/hip_runtime.h>
#include <hip/hip_bf16.h>
#include <stdint.h>

typedef __attribute__((ext_vector_type(8))) short short8;
typedef __attribute__((ext_vector_type(4))) float f32x4;
typedef unsigned short u16;

#define MFMA16(a,b,c) __builtin_amdgcn_mfma_f32_16x16x32_bf16((a),(b),(c),0,0,0)

__device__ __forceinline__ u16 f2bf(float f) {           // RNE f32->bf16
  unsigned int u = __float_as_uint(f);
  return (u16)((u + 0x7FFFu + ((u >> 16) & 1u)) >> 16);
}
__device__ __forceinline__ float bf2f(u16 h) {
  return __uint_as_float(((unsigned int)h) << 16);
}
__device__ __forceinline__ float clampf(float v, float lo, float hi) {
  return fminf(fmaxf(v, lo), hi);
}
__device__ __forceinline__ void gl2lds16(const u16* g, u16* l) {
  __builtin_amdgcn_global_load_lds(
      (const __attribute__((address_space(1))) unsigned int*)g,
      (__attribute__((address_space(3))) unsigned int*)(uintptr_t)l,
      16, 0, 0);
}

// ---------------------------------------------------------------- convert
__global__ __launch_bounds__(256) void cvt_bf16_kernel(
    const float* __restrict__ src, u16* __restrict__ dst, int n) {
  for (int i = blockIdx.x*256 + threadIdx.x; i < n; i += gridDim.x*256)
    dst[i] = f2bf(src[i]);
}

// ---------------------------------------------------------------- embed
__global__ __launch_bounds__(256) void embed_kernel(
    const int* __restrict__ iseq, const float* __restrict__ emb,
    u16* __restrict__ xb) {
  int gid = blockIdx.x*256 + threadIdx.x;
  int m = gid >> 7;
  int c = (gid & 127) * 4;
  int item = iseq[m];
  float4 e = *(const float4*)&emb[(size_t)item*512 + c];
  ushort4 hb;
  hb.x = f2bf(clampf(e.x*0.5f, -1.f, 1.f));
  hb.y = f2bf(clampf(e.y*0.5f, -1.f, 1.f));
  hb.z = f2bf(clampf(e.z*0.5f, -1.f, 1.f));
  hb.w = f2bf(clampf(e.w*0.5f, -1.f, 1.f));
  *(ushort4*)&xb[(size_t)m*512 + c] = hb;
}

// ---------------------------------------------------------------- valid count per batch
__global__ __launch_bounds__(256) void cnt_kernel(
    const int* __restrict__ item_seq, float* __restrict__ cnt) {
  __shared__ int sred[4];
  int b = blockIdx.x, tid = threadIdx.x;
  int lane = tid & 63, wv = tid >> 6;
  int c = 0;
  if (tid < 200) c = (item_seq[b*200 + tid] != 0) ? 1 : 0;
  #pragma unroll
  for (int m = 1; m <= 32; m <<= 1) c += __shfl_xor(c, m);
  if (lane == 0) sred[wv] = c;
  __syncthreads();
  if (tid == 0) cnt[b] = (float)(sred[0]+sred[1]+sred[2]+sred[3]);
}

// ---------------------------------------------------------------- GEMM  C = A @ W^T
// 256x256 tile, BK=64, 8 waves (2M x 4N). SINGLE-buffered 64 KiB LDS
// (A 32K + B 32K) -> 2 blocks/CU: cross-block MFMA/stall overlap (m114) is
// the latency-hiding mechanism instead of intra-block pipelining. Per K-tile:
//   {24 ds_reads -> 64 MFMA} ; BAR ; stage(t+1) ; vmcnt(0) ; BAR
// Reads are consumed by MFMA before the barrier (complete), so the re-stage
// WAR is safe; vmcnt(0)+BAR makes staging visible to all waves.
// XOR-swizzled LDS (T2, same both-sides scheme), setprio (T5), XCD swz (T1),
// coalesced LDS-retranspose epilogue (LROW=256, fits the 64 KiB).
// MODE 0: QKV scatter; 1: out_proj; 2: lin1+relu; 3: lin2.
#define BAR() asm volatile("s_barrier" ::: "memory")
#define VMW(N) asm volatile("s_waitcnt vmcnt(" #N ")" ::: "memory")

// Stage one half-tile (128 rows x 64 cols bf16 = 16 KiB) linearly into LDS,
// with the global SOURCE pre-swizzled so that LDS physical layout matches
// the XOR-swizzled read path (rule #21: both-sides-or-neither).
__device__ __forceinline__ void stage_half(const char* gsrc0, size_t rstride,
                                           u16* lhalf, int wv, int lane) {
  #pragma unroll
  for (int j = 0; j < 2; ++j) {
    const int o   = j*8192 + wv*1024 + lane*16;   // dest byte offset (linear)
    const int row = o >> 7;                        // 128 B per row
    const int cb  = (o & 127) ^ ((row & 7) << 4);  // inverse-swizzled src col
    gl2lds16((const u16*)(gsrc0 + (size_t)row*rstride + cb),
             (u16*)((char*)lhalf + j*8192 + wv*1024));
  }
}

// Swizzled ds_read_b128 of one MFMA fragment. kb = byte col (mult of 16).
__device__ __forceinline__ short8 ldsfrag(const u16* slot, int row, int kb) {
  return *(const short8*)((const char*)slot + row*128 + (kb ^ ((row & 7) << 4)));
}

template <int MODE>
__global__ __launch_bounds__(512, 2)
void gemm_bt(const u16* __restrict__ A, const u16* __restrict__ Bw,
             const float* __restrict__ bias, int K, int Nt, int swz,
             u16* __restrict__ outB, u16* __restrict__ QKV, long long projStride) {
  __shared__ __align__(16) u16 SH[32768];       // 64 KiB exactly
  u16* const As = SH;                           // 32 KiB: 256 rows x 64 cols
  u16* const Bs = SH + 16384;                   // 32 KiB
  const int tid  = threadIdx.x;
  const int lane = tid & 63;
  const int wv   = tid >> 6;          // 0..7
  const int wm   = wv >> 2;           // 0..1  (128-row half)
  const int wn   = wv & 3;            // 0..3  (64-col strip)
  const int id   = blockIdx.x;
  int mt, nt2;
  if (swz) { mt = (id / (8*Nt))*8 + (id & 7); nt2 = (id >> 3) % Nt; }
  else     { mt = id / Nt;                    nt2 = id % Nt; }
  const int m0 = mt * 256;
  const int n0 = nt2 * 256;
  const int KT = K >> 6;              // K-tiles of 64

  const char* Abase = (const char*)(A  + (size_t)m0*K);
  const char* Bbase = (const char*)(Bw + (size_t)n0*K);
  const size_t rs = (size_t)K * 2;

  const int r16 = lane & 15;
  const int q4  = lane >> 4;

  const f32x4 fz = {0.f, 0.f, 0.f, 0.f};
  f32x4 acc[8][4];
  #pragma unroll
  for (int i = 0; i < 8; ++i)
    #pragma unroll
    for (int j = 0; j < 4; ++j) acc[i][j] = fz;

  short8 af[2][4][2];
  short8 bf[4][2];

  // ---- prologue: stage tile 0 (A + B), drain, barrier
  stage_half(Abase,            rs, As,           wv, lane);
  stage_half(Abase + 128*rs,   rs, As + 128*64,  wv, lane);
  stage_half(Bbase,            rs, Bs,           wv, lane);
  stage_half(Bbase + 128*rs,   rs, Bs + 128*64,  wv, lane);
  VMW(0);
  BAR();

  for (int t = 0; t < KT; ++t) {
    // reads for tile t (consumed by MFMA below -> complete before barrier)
    #pragma unroll
    for (int h = 0; h < 2; ++h)
      #pragma unroll
      for (int i = 0; i < 4; ++i)
        #pragma unroll
        for (int ks = 0; ks < 2; ++ks)
          af[h][i][ks] = ldsfrag(As, wm*128 + h*64 + i*16 + r16, ks*64 + q4*16);
    #pragma unroll
    for (int nf = 0; nf < 4; ++nf)
      #pragma unroll
      for (int ks = 0; ks < 2; ++ks)
        bf[nf][ks] = ldsfrag(Bs, wn*64 + nf*16 + r16, ks*64 + q4*16);

    __builtin_amdgcn_s_setprio(1);
    #pragma unroll
    for (int h = 0; h < 2; ++h)
      #pragma unroll
      for (int i = 0; i < 4; ++i)
        #pragma unroll
        for (int nf = 0; nf < 4; ++nf)
          #pragma unroll
          for (int ks = 0; ks < 2; ++ks)
            acc[h*4 + i][nf] = MFMA16(af[h][i][ks], bf[nf][ks], acc[h*4 + i][nf]);
    __builtin_amdgcn_s_setprio(0);

    if (t + 1 < KT) {
      BAR();                                     // all waves done reading tile t
      const char* Ag = Abase + (size_t)(t+1)*128;
      const char* Bg = Bbase + (size_t)(t+1)*128;
      stage_half(Ag,            rs, As,           wv, lane);
      stage_half(Ag + 128*rs,   rs, As + 128*64,  wv, lane);
      stage_half(Bg,            rs, Bs,           wv, lane);
      stage_half(Bg + 128*rs,   rs, Bs + 128*64,  wv, lane);
      VMW(0);
      BAR();                                     // tile t+1 visible to all
    }
  }

  // ---- epilogue: LDS-retranspose coalesced stores (LROW=256, 64 KiB) ----
  __syncthreads();                               // all waves done with As/Bs
  {
    u16* const L = SH;
    const int LROW = 256;
    #pragma unroll
    for (int h = 0; h < 2; ++h) {
      if (h == 1) __syncthreads();               // protect L reuse across passes
      if (wm == h) {
        #pragma unroll
        for (int nf = 0; nf < 4; ++nf) {
          const int col_l = wn*64 + nf*16 + r16;
          const float bvs = (MODE == 0) ? 0.f : bias[n0 + col_l];
          #pragma unroll
          for (int mi = 0; mi < 8; ++mi) {
            const int row_l = mi*16 + q4*4;
            #pragma unroll
            for (int r = 0; r < 4; ++r) {
              float v = acc[mi][nf][r];
              if (MODE == 0)      v = clampf(v, -1.f, 1.f);
              else if (MODE == 1) v = clampf(v + bvs, -3.f, 3.f);
              else if (MODE == 2) v = fmaxf(clampf(v + bvs, -2.f, 2.f), 0.f);
              else                v = clampf(v + bvs, -2.f, 2.f);
              L[(row_l + r)*LROW + col_l] = f2bf(v);
            }
          }
        }
      }
      __syncthreads();
      #pragma unroll
      for (int k = 0; k < 8; ++k) {
        const int ch   = wv*512 + k*64 + lane;   // 16B chunk id (0..4095)
        const int row  = ch >> 5;                // 32 chunks per 256-col row
        const int colu = (ch & 31) * 8;          // u16 col
        short8 d = *(const short8*)&L[row*LROW + colu];
        const int rowg = m0 + h*128 + row;
        const int cg   = n0 + colu;
        if (MODE == 0) {
          const unsigned proj = (unsigned)cg >> 9;
          const unsigned hh   = ((unsigned)cg >> 6) & 7u;
          const unsigned dk   = (unsigned)cg & 63u;
          const int b = rowg / 200;
          const int s = rowg - b*200;
          *(short8*)&QKV[(size_t)proj*projStride + (size_t)hh*12800
                         + (size_t)b*102400 + (size_t)s*64 + dk] = d;
        } else {
          const int N = (MODE == 2) ? 1024 : 512;
          *(short8*)&outB[(size_t)rowg*N + cg] = d;
        }
      }
    }
  }
}

// ---------------------------------------------------------------- fused attention
// 8 waves / 512 threads: 2 q-blocks of 128 rows. LDS ~70.7 KB -> 2 blocks/CU,
// 16 waves/CU. V-transpose staging conflict-free (lanes write consecutive s).
__global__ __launch_bounds__(512)
void attn_kernel(const u16* __restrict__ Q, const u16* __restrict__ K,
                 const u16* __restrict__ V, const int* __restrict__ iseq,
                 u16* __restrict__ x2b) {
  __shared__ __align__(16) u16 Ks[208*72];
  __shared__ __align__(16) u16 Vs[64*232];
  __shared__ __align__(16) u16 Ps[8][16*40];
  __shared__ float msk[208];

  const int tid = threadIdx.x, lane = tid & 63, wv = tid >> 6;
  const unsigned bid = blockIdx.x;
  const int h = bid & 7;
  const int b = bid >> 3;
  const size_t bh = (size_t)b*8 + h;
  const u16* Kg = K + bh*12800;
  const u16* Vg = V + bh*12800;
  const u16* Qg = Q + bh*12800;

  for (int c = tid; c < 3200; c += 512) {       // K -> Ks[key][dk]
    int row = c >> 4, q = c & 15;
    *(ushort4*)&Ks[row*72 + q*4] = *(const ushort4*)&Kg[row*64 + q*4];
  }
  // V -> Vs[dk][s] transpose: wave w owns d-quads {2w, 2w+1}; lanes walk
  // consecutive s -> contiguous u16 LDS stores (no bank conflicts).
  {
    const int quad = wv*2 + (lane >> 5);        // 0..15
    const int sl   = lane & 31;
    #pragma unroll
    for (int it = 0; it < 7; ++it) {
      const int s = sl + it*32;
      if (s < 200) {
        ushort4 v4 = *(const ushort4*)&Vg[s*64 + quad*4];
        Vs[(quad*4+0)*232 + s] = v4.x;
        Vs[(quad*4+1)*232 + s] = v4.y;
        Vs[(quad*4+2)*232 + s] = v4.z;
        Vs[(quad*4+3)*232 + s] = v4.w;
      }
    }
  }
  for (int c = tid; c < 2048; c += 512) {
    int dk = c >> 5, s2 = 200 + (c & 31);
    Vs[dk*232 + s2] = 0;
  }
  for (int t = tid; t < 208; t += 512)
    msk[t] = (t < 200 && iseq[b*200 + t] != 0) ? 1.f : 0.f;
  __syncthreads();

  const int colk = lane & 15;
  const int fk8 = (lane >> 4) * 8;
  const int prow = (lane >> 4) * 4;
  const f32x4 fz = {0.f,0.f,0.f,0.f};

  for (int qb = 0; qb < 2; ++qb) {
    const int qrow = qb*128 + wv*16 + (lane & 15);
    const int qsrc = qrow < 200 ? qrow : 199;
    short8 qa0 = *(const short8*)&Qg[(size_t)qsrc*64 + fk8];
    short8 qa1 = *(const short8*)&Qg[(size_t)qsrc*64 + 32 + fk8];
    f32x4 oacc[4];
    #pragma unroll
    for (int nt = 0; nt < 4; ++nt) oacc[nt] = fz;
    float rs[4] = {0.f,0.f,0.f,0.f};

    for (int kt2 = 0; kt2 < 7; ++kt2) {
      #pragma unroll
      for (int half = 0; half < 2; ++half) {
        const int stile = kt2*2 + half;
        if (stile < 13) {
          const int key = stile*16 + colk;
          short8 kb0 = *(const short8*)&Ks[key*72 + fk8];
          short8 kb1 = *(const short8*)&Ks[key*72 + 32 + fk8];
          f32x4 sc = fz;
          __builtin_amdgcn_s_setprio(1);
          sc = MFMA16(qa0, kb0, sc);
          sc = MFMA16(qa1, kb1, sc);
          __builtin_amdgcn_s_setprio(0);
          const float mk = msk[key];
          #pragma unroll
          for (int r = 0; r < 4; ++r) {
            float p = __expf(clampf(sc[r]*2.5f, -3.f, 3.f)) * mk;
            rs[r] += p;
            Ps[wv][(prow + r)*40 + half*16 + colk] = f2bf(p);
          }
        } else {
          #pragma unroll
          for (int r = 0; r < 4; ++r)
            Ps[wv][(prow + r)*40 + half*16 + colk] = 0;
        }
      }
      asm volatile("s_waitcnt lgkmcnt(0)" ::: "memory");
      short8 pa = *(const short8*)&Ps[wv][(lane & 15)*40 + fk8];
      const int kb32 = kt2*32;
      __builtin_amdgcn_s_setprio(1);
      #pragma unroll
      for (int nt = 0; nt < 4; ++nt) {
        short8 vb = *(const short8*)&Vs[(nt*16 + colk)*232 + kb32 + fk8];
        oacc[nt] = MFMA16(pa, vb, oacc[nt]);
      }
      __builtin_amdgcn_s_setprio(0);
      asm volatile("s_waitcnt lgkmcnt(0)" ::: "memory");
    }

    #pragma unroll
    for (int m = 1; m <= 8; m <<= 1)
      #pragma unroll
      for (int r = 0; r < 4; ++r) rs[r] += __shfl_xor(rs[r], m);

    const int srow = qb*128 + wv*16 + prow;
    #pragma unroll
    for (int r = 0; r < 4; ++r) {
      const int s = srow + r;
      if (s < 200) {
        const float inv = rs[r] > 0.f ? 1.f/rs[r] : 0.f;
        const size_t base = ((size_t)b*200 + s)*512 + h*64;
        #pragma unroll
        for (int nt = 0; nt < 4; ++nt)
          x2b[base + nt*16 + colk] = f2bf(oacc[nt][r] * inv);
      }
    }
  }
}

// ---------------------------------------------------------------- LN1 (double): xn = LN(x + LN(x+x2)); x from xb (bf16)
__global__ __launch_bounds__(256)
void ln1_kernel(const u16* __restrict__ xb, const u16* __restrict__ x2b,
                const float* __restrict__ g, const float* __restrict__ bb,
                u16* __restrict__ xnb) {
  const int lane = threadIdx.x & 63, wv = threadIdx.x >> 6;
  const size_t t = (size_t)blockIdx.x*4 + wv;
  const int c0 = lane*4, c1 = 256 + lane*4;
  ushort4 xa = *(const ushort4*)&xb[t*512 + c0];
  ushort4 xc = *(const ushort4*)&xb[t*512 + c1];
  ushort4 ha = *(const ushort4*)&x2b[t*512 + c0];
  ushort4 hc = *(const ushort4*)&x2b[t*512 + c1];
  float xv[8] = {bf2f(xa.x),bf2f(xa.y),bf2f(xa.z),bf2f(xa.w),
                 bf2f(xc.x),bf2f(xc.y),bf2f(xc.z),bf2f(xc.w)};
  float tv[8] = {xv[0]+bf2f(ha.x), xv[1]+bf2f(ha.y), xv[2]+bf2f(ha.z), xv[3]+bf2f(ha.w),
                 xv[4]+bf2f(hc.x), xv[5]+bf2f(hc.y), xv[6]+bf2f(hc.z), xv[7]+bf2f(hc.w)};
  float s1 = 0.f, s2 = 0.f;
  #pragma unroll
  for (int i = 0; i < 8; ++i) { s1 += tv[i]; s2 += tv[i]*tv[i]; }
  #pragma unroll
  for (int m = 1; m <= 32; m <<= 1) { s1 += __shfl_xor(s1, m); s2 += __shfl_xor(s2, m); }
  float mean = s1*(1.f/512.f);
  float inv = 1.f/sqrtf(s2*(1.f/512.f) - mean*mean + 1e-6f);
  float4 ga = *(const float4*)(g + c0), gc = *(const float4*)(g + c1);
  float4 ba = *(const float4*)(bb + c0), bc = *(const float4*)(bb + c1);
  float gv[8] = {ga.x,ga.y,ga.z,ga.w, gc.x,gc.y,gc.z,gc.w};
  float bv[8] = {ba.x,ba.y,ba.z,ba.w, bc.x,bc.y,bc.z,bc.w};
  float uv[8]; float s3 = 0.f, s4 = 0.f;
  #pragma unroll
  for (int i = 0; i < 8; ++i) {
    float sa = (tv[i]-mean)*inv*gv[i] + bv[i];
    uv[i] = xv[i] + sa;
    s3 += uv[i]; s4 += uv[i]*uv[i];
  }
  #pragma unroll
  for (int m = 1; m <= 32; m <<= 1) { s3 += __shfl_xor(s3, m); s4 += __shfl_xor(s4, m); }
  float mean2 = s3*(1.f/512.f);
  float inv2 = 1.f/sqrtf(s4*(1.f/512.f) - mean2*mean2 + 1e-6f);
  ushort4 o0, o1;
  o0.x = f2bf((uv[0]-mean2)*inv2*gv[0] + bv[0]);
  o0.y = f2bf((uv[1]-mean2)*inv2*gv[1] + bv[1]);
  o0.z = f2bf((uv[2]-mean2)*inv2*gv[2] + bv[2]);
  o0.w = f2bf((uv[3]-mean2)*inv2*gv[3] + bv[3]);
  o1.x = f2bf((uv[4]-mean2)*inv2*gv[4] + bv[4]);
  o1.y = f2bf((uv[5]-mean2)*inv2*gv[5] + bv[5]);
  o1.z = f2bf((uv[6]-mean2)*inv2*gv[6] + bv[6]);
  o1.w = f2bf((uv[7]-mean2)*inv2*gv[7] + bv[7]);
  *(ushort4*)&xnb[t*512 + c0] = o0;
  *(ushort4*)&xnb[t*512 + c1] = o1;
}

// ---------------------------------------------------------------- LN2 (double) + masked partials — barrier-free
__global__ __launch_bounds__(256)
void ln2_kernel(const u16* __restrict__ xnb, const u16* __restrict__ f2b,
                const float* __restrict__ g, const float* __restrict__ bb,
                const int* __restrict__ iseq, float* __restrict__ seq_acc) {
  const int tid = threadIdx.x, lane = tid & 63, wv = tid >> 6;
  const int q = blockIdx.x, bl = blockIdx.y;
  const int c8 = lane*8;
  float gv[8], bv[8];
  *(float4*)&gv[0] = *(const float4*)(g + c8);
  *(float4*)&gv[4] = *(const float4*)(g + c8 + 4);
  *(float4*)&bv[0] = *(const float4*)(bb + c8);
  *(float4*)&bv[4] = *(const float4*)(bb + c8 + 4);
  float acc[8] = {};
  for (int i = wv; i < 50; i += 4) {
    const int s = q*50 + i;
    const size_t row = (size_t)bl*200 + s;
    short8 xh = *(const short8*)&xnb[row*512 + c8];
    short8 yh = *(const short8*)&f2b[row*512 + c8];
    float xv[8], tv[8];
    #pragma unroll
    for (int j = 0; j < 8; ++j) {
      xv[j] = bf2f((u16)xh[j]);
      tv[j] = xv[j] + bf2f((u16)yh[j]);
    }
    float s1 = 0.f, s2 = 0.f;
    #pragma unroll
    for (int j = 0; j < 8; ++j) { s1 += tv[j]; s2 += tv[j]*tv[j]; }
    #pragma unroll
    for (int m = 1; m <= 32; m <<= 1) { s1 += __shfl_xor(s1,m); s2 += __shfl_xor(s2,m); }
    float mean = s1*(1.f/512.f);
    float inv = 1.f/sqrtf(s2*(1.f/512.f) - mean*mean + 1e-6f);
    float uv[8]; float s3 = 0.f, s4 = 0.f;
    #pragma unroll
    for (int j = 0; j < 8; ++j) {
      uv[j] = xv[j] + (tv[j]-mean)*inv*gv[j] + bv[j];
      s3 += uv[j]; s4 += uv[j]*uv[j];
    }
    #pragma unroll
    for (int m = 1; m <= 32; m <<= 1) { s3 += __shfl_xor(s3,m); s4 += __shfl_xor(s4,m); }
    float mean2 = s3*(1.f/512.f);
    float inv2 = 1.f/sqrtf(s4*(1.f/512.f) - mean2*mean2 + 1e-6f);
    if (iseq[row] != 0) {
      #pragma unroll
      for (int j = 0; j < 8; ++j)
        acc[j] += clampf((uv[j]-mean2)*inv2*gv[j] + bv[j], -5.f, 5.f);
    }
  }
  float* dst = &seq_acc[(((size_t)bl*4 + q)*4 + wv)*512 + c8];
  *(float4*)&dst[0] = *(float4*)&acc[0];
  *(float4*)&dst[4] = *(float4*)&acc[4];
}

// ---------------------------------------------------------------- assemble user vector u (512 x 1152)
__global__ __launch_bounds__(256)
void build_u_kernel(const float* __restrict__ seq_acc, const float* __restrict__ cnt,
                    const float* __restrict__ uac, const float* __restrict__ uti,
                    const int* __restrict__ age, const int* __restrict__ gen,
                    const int* __restrict__ cms,
                    const float* __restrict__ age_tab, const float* __restrict__ gen_tab,
                    const float* __restrict__ cms_tab,
                    const float* __restrict__ ctr_w, const float* __restrict__ ctr_b,
                    const float* __restrict__ ti_w, const float* __restrict__ ti_b,
                    float* __restrict__ u) {
  const int b = blockIdx.x;
  for (int j = threadIdx.x; j < 1152; j += 256) {
    float v;
    if (j < 512) {
      float ssum = 0.f;
      #pragma unroll
      for (int p = 0; p < 16; ++p) ssum += seq_acc[((size_t)b*16 + p)*512 + j];
      v = clampf(ssum / (cnt[b] + 1e-8f), -5.f, 5.f);
    }
    else if (j < 640)  { int e = j-512;  v = uac[b]*ctr_w[e] + ctr_b[e]; }
    else if (j < 768)  { int e = j-640;  v = uti[b]*ti_w[e] + ti_b[e]; }
    else if (j < 896)  { int e = j-768;  v = age_tab[age[b]*128 + e]; }
    else if (j < 1024) { int e = j-896;  v = gen_tab[gen[b]*128 + e]; }
    else               { int e = j-1024; v = cms_tab[cms[b]*128 + e]; }
    u[(size_t)b*1152 + j] = v;
  }
}

// ---------------------------------------------------------------- mlp1
__global__ __launch_bounds__(256)
void mlp1_kernel(const float* __restrict__ u, const float* __restrict__ w,
                 const float* __restrict__ bias, float* __restrict__ h1) {
  __shared__ __align__(16) float As[64][36];
  __shared__ __align__(16) float Wt[32][68];
  const int tid = threadIdx.x;
  const int m0 = blockIdx.x*64, n0 = blockIdx.y*64;
  const int tm = tid >> 4, tn = tid & 15;
  float acc[4][4] = {};
  for (int k0 = 0; k0 < 1152; k0 += 32) {
    for (int c = tid; c < 512; c += 256) {
      int row = c >> 3, q = c & 7;
      *(float4*)&As[row][q*4] = *(const float4*)&u[(size_t)(m0+row)*1152 + k0 + q*4];
      float4 wv4 = *(const float4*)&w[(size_t)(n0+row)*1152 + k0 + q*4];
      Wt[q*4+0][row] = wv4.x; Wt[q*4+1][row] = wv4.y;
      Wt[q*4+2][row] = wv4.z; Wt[q*4+3][row] = wv4.w;
    }
    __syncthreads();
    #pragma unroll
    for (int kk = 0; kk < 32; ++kk) {
      float av[4], bw[4];
      #pragma unroll
      for (int i = 0; i < 4; ++i) av[i] = As[tm*4+i][kk];
      #pragma unroll
      for (int j = 0; j < 4; ++j) bw[j] = Wt[kk][tn*4+j];
      #pragma unroll
      for (int i = 0; i < 4; ++i)
        #pragma unroll
        for (int j = 0; j < 4; ++j) acc[i][j] += av[i]*bw[j];
    }
    __syncthreads();
  }
  #pragma unroll
  for (int i = 0; i < 4; ++i)
    #pragma unroll
    for (int j = 0; j < 4; ++j) {
      int n = n0 + tn*4 + j;
      h1[(size_t)(m0 + tm*4 + i)*1024 + n] = fmaxf(acc[i][j] + bias[n], 0.f);
    }
}

// ---------------------------------------------------------------- mlp2
__global__ __launch_bounds__(256)
void mlp2_kernel(const float* __restrict__ h1, const float* __restrict__ w,
                 const float* __restrict__ bias, float* __restrict__ out) {
  const int tid = threadIdx.x;
  const int m = blockIdx.x*4 + (tid >> 6);
  const int n = tid & 63;
  const float4* hr = (const float4*)(h1 + (size_t)m*1024);
  const float4* wr = (const float4*)(w + (size_t)n*1024);
  float acc = 0.f;
  for (int k4 = 0; k4 < 256; ++k4) {
    float4 a = hr[k4], bw = wr[k4];
    acc += a.x*bw.x + a.y*bw.y + a.z*bw.z + a.w*bw.w;
  }
  out[(size_t)m*64 + n] = acc + bias[n];
}

// ================================================================ launch
extern "C" void kernel_launch(void* const* d_in, const int* in_sizes, int n_in,
                              void* d_out, int out_size, void* d_ws, size_t ws_size,
                              hipStream_t stream) {
  (void)in_sizes; (void)n_in; (void)out_size;
  const int*   item_seq   = (const int*)d_in[0];
  const float* uac        = (const float*)d_in[1];
  const float* uti        = (const float*)d_in[2];
  const int*   age        = (const int*)d_in[3];
  const int*   gen        = (const int*)d_in[4];
  const int*   cms        = (const int*)d_in[5];
  const float* emb        = (const float*)d_in[6];
  const float* in_proj_w  = (const float*)d_in[7];
  const float* out_proj_w = (const float*)d_in[8];
  const float* out_proj_b = (const float*)d_in[9];
  const float* ln1_g = (const float*)d_in[10];
  const float* ln1_b = (const float*)d_in[11];
  const float* ln2_g = (const float*)d_in[12];
  const float* ln2_b = (const float*)d_in[13];
  const float* lin1_w = (const float*)d_in[14];
  const float* lin1_b = (const float*)d_in[15];
  const float* lin2_w = (const float*)d_in[16];
  const float* lin2_b = (const float*)d_in[17];
  const float* age_tab = (const float*)d_in[18];
  const float* gen_tab = (const float*)d_in[19];
  const float* cms_tab = (const float*)d_in[20];
  const float* ctr_w = (const float*)d_in[21];
  const float* ctr_b = (const float*)d_in[22];
  const float* ti_w  = (const float*)d_in[23];
  const float* ti_b  = (const float*)d_in[24];
  const float* mlp1_w = (const float*)d_in[25];
  const float* mlp1_b = (const float*)d_in[26];
  const float* mlp2_w = (const float*)d_in[27];
  const float* mlp2_b = (const float*)d_in[28];

  // ---- adaptive chunking: 5 regions of CB*200*512*2 B each + tail ----
  const long long TAILB = 25430016LL;
  int CB = 32;
  if      ((long long)ws_size >= 512LL*1024000 + TAILB) CB = 512;  // 549.7 MB (ws ~819 MB)
  else if ((long long)ws_size >= 128LL*1024000 + TAILB) CB = 128;
  else if ((long long)ws_size >=  64LL*1024000 + TAILB) CB = 64;
  const long long R = (long long)CB * 204800;

  char* ws = (char*)d_ws;
  u16* xb   = (u16*)(ws);            // region 0: embed bf16 (live through ln1)
  u16* x2b  = (u16*)(ws + R);        // region 1: attn out
  u16* Qb   = (u16*)(ws + 2*R);      // region 2: Q; later x2o
  u16* Kb   = (u16*)(ws + 3*R);      // region 3: K; later xnb
  u16* Vrb  = (u16*)(ws + 4*R);      // region 4: V; later f2b
  u16* x2o  = Qb;
  u16* xnb  = Kb;
  u16* f2b  = Vrb;
  u16* hbuf = (u16*)(ws);            // regions 0-1 (xb,x2b dead after ln1)
  char* tail = ws + 5*R;
  float* seq_acc = (float*)(tail);              // 16,777,216  [B][16][512]
  float* cnt     = (float*)(tail + 16777216);   // 2,048
  float* u       = (float*)(tail + 16779264);   // 2,359,296
  float* h1      = (float*)(tail + 19138560);   // 2,097,152
  u16*   wqkv    = (u16*)(tail + 21235712);     // 1,572,864
  u16*   wout    = (u16*)(tail + 22808576);     // 524,288
  u16*   wl1     = (u16*)(tail + 23332864);     // 1,048,576
  u16*   wl2     = (u16*)(tail + 24381440);     // 1,048,576 -> 25,430,016

  cvt_bf16_kernel<<<768, 256, 0, stream>>>(in_proj_w, wqkv, 1536*512);
  cvt_bf16_kernel<<<256, 256, 0, stream>>>(out_proj_w, wout, 512*512);
  cvt_bf16_kernel<<<512, 256, 0, stream>>>(lin1_w, wl1, 1024*512);
  cvt_bf16_kernel<<<512, 256, 0, stream>>>(lin2_w, wl2, 512*1024);
  cnt_kernel<<<512, 256, 0, stream>>>(item_seq, cnt);

  const int nch = 512 / CB;
  const int Mc  = CB * 200;
  const int Mt  = Mc / 256;                    // 256-row tiles
  const int swz = (Mt % 8 == 0) ? 1 : 0;
  const long long projStride = (long long)CB * 102400;
  for (int ch = 0; ch < nch; ++ch) {
    const int* iseq = item_seq + (size_t)ch*CB*200;
    embed_kernel<<<Mc/2, 256, 0, stream>>>(iseq, emb, xb);
    gemm_bt<0><<<Mt*6, 512, 0, stream>>>(xb, wqkv, nullptr, 512, 6, swz,
                                         nullptr, Qb, projStride);
    attn_kernel<<<CB*8, 512, 0, stream>>>(Qb, Kb, Vrb, iseq, x2b);
    gemm_bt<1><<<Mt*2, 512, 0, stream>>>(x2b, wout, out_proj_b, 512, 2, swz,
                                         x2o, nullptr, 0);
    ln1_kernel<<<Mc/4, 256, 0, stream>>>(xb, x2o, ln1_g, ln1_b, xnb);
    gemm_bt<2><<<Mt*4, 512, 0, stream>>>(xnb, wl1, lin1_b, 512, 4, swz,
                                         hbuf, nullptr, 0);
    gemm_bt<3><<<Mt*2, 512, 0, stream>>>(hbuf, wl2, lin2_b, 1024, 2, swz,
                                         f2b, nullptr, 0);
    ln2_kernel<<<dim3(4, CB), 256, 0, stream>>>(xnb, f2b, ln2_g, ln2_b, iseq,
                                                seq_acc + (size_t)ch*CB*8192);
  }

  build_u_kernel<<<512, 256, 0, stream>>>(seq_acc, cnt, uac, uti, age, gen, cms,
                                          age_tab, gen_tab, cms_tab,
                                          ctr_w, ctr_b, ti_w, ti_b, u);
  mlp1_kernel<<<dim3(8, 16), 256, 0, stream>>>(u, mlp1_w, mlp1_b, h1);
  mlp2_kernel<<<128, 256, 0, stream>>>(h1, mlp2_w, mlp2_b, (float*)d_out);
}

// Round 8
// 1386.855 us; speedup vs baseline: 1.1888x; 1.1097x over previous
//
#include <hip/hip_runtime.h>
#include <hip/hip_bf16.h>
#include <stdint.h>

typedef __attribute__((ext_vector_type(8))) short short8;
typedef __attribute__((ext_vector_type(4))) float f32x4;
typedef unsigned short u16;

#define MFMA16(a,b,c) __builtin_amdgcn_mfma_f32_16x16x32_bf16((a),(b),(c),0,0,0)

__device__ __forceinline__ u16 f2bf(float f) {           // RNE f32->bf16
  unsigned int u = __float_as_uint(f);
  return (u16)((u + 0x7FFFu + ((u >> 16) & 1u)) >> 16);
}
__device__ __forceinline__ float bf2f(u16 h) {
  return __uint_as_float(((unsigned int)h) << 16);
}
__device__ __forceinline__ float clampf(float v, float lo, float hi) {
  return fminf(fmaxf(v, lo), hi);
}
__device__ __forceinline__ void gl2lds16(const u16* g, u16* l) {
  __builtin_amdgcn_global_load_lds(
      (const __attribute__((address_space(1))) unsigned int*)g,
      (__attribute__((address_space(3))) unsigned int*)(uintptr_t)l,
      16, 0, 0);
}

// ---------------------------------------------------------------- convert
__global__ __launch_bounds__(256) void cvt_bf16_kernel(
    const float* __restrict__ src, u16* __restrict__ dst, int n) {
  for (int i = blockIdx.x*256 + threadIdx.x; i < n; i += gridDim.x*256)
    dst[i] = f2bf(src[i]);
}

// ---------------------------------------------------------------- embed
__global__ __launch_bounds__(256) void embed_kernel(
    const int* __restrict__ iseq, const float* __restrict__ emb,
    u16* __restrict__ xb) {
  int gid = blockIdx.x*256 + threadIdx.x;
  int m = gid >> 7;
  int c = (gid & 127) * 4;
  int item = iseq[m];
  float4 e = *(const float4*)&emb[(size_t)item*512 + c];
  ushort4 hb;
  hb.x = f2bf(clampf(e.x*0.5f, -1.f, 1.f));
  hb.y = f2bf(clampf(e.y*0.5f, -1.f, 1.f));
  hb.z = f2bf(clampf(e.z*0.5f, -1.f, 1.f));
  hb.w = f2bf(clampf(e.w*0.5f, -1.f, 1.f));
  *(ushort4*)&xb[(size_t)m*512 + c] = hb;
}

// ---------------------------------------------------------------- valid count per batch
__global__ __launch_bounds__(256) void cnt_kernel(
    const int* __restrict__ item_seq, float* __restrict__ cnt) {
  __shared__ int sred[4];
  int b = blockIdx.x, tid = threadIdx.x;
  int lane = tid & 63, wv = tid >> 6;
  int c = 0;
  if (tid < 200) c = (item_seq[b*200 + tid] != 0) ? 1 : 0;
  #pragma unroll
  for (int m = 1; m <= 32; m <<= 1) c += __shfl_xor(c, m);
  if (lane == 0) sred[wv] = c;
  __syncthreads();
  if (tid == 0) cnt[b] = (float)(sred[0]+sred[1]+sred[2]+sred[3]);
}

// ---------------------------------------------------------------- GEMM  C = A @ W^T
// 256x256 tile, BK=64, 8 waves (2M x 4N), double-buffered 128 KiB LDS.
// m201 8-phase sandwich. THIS ROUND: vmcnt ONLY at ph4/ph8 (m201 rule:
// "vmcnt(N) only at phases 4 and 8, never 0 in main loop"). Prior rounds
// placed vmcnt(4) at every phase-end, gating on ~2-phase-old L3 loads
// (~900cyc latency, ~0 slack). FIFO ledger (steady state, 2 loads/stage):
//   ph4-end outstanding {prev-b'A(4), b.B(4), a'A(4)} -> VM4 forces
//   prev-b'A + b.B (needed ph5), leaves a'A flying.
//   ph8-end outstanding {a'A(4), a'B(4), b'A(4)} -> VM4 forces a'A + a'B
//   (needed next ph1), leaves b'A flying.
// Tail: final iter ph4 -> VM0 (at 8 outstanding VM4 would leave b.B).
// WAR slots unchanged from round-4 map (each staged region's reads complete
// >=1 barrier-pair earlier). Epilogue: LDS-retranspose coalesced stores.
// MODE 0: QKV scatter; 1: out_proj; 2: lin1+relu; 3: lin2.
#define BAR() asm volatile("s_barrier" ::: "memory")
#define LGKM0() do { asm volatile("s_waitcnt lgkmcnt(0)" ::: "memory"); \
                     __builtin_amdgcn_sched_barrier(0); } while (0)
#define VM4() asm volatile("s_waitcnt vmcnt(4)" ::: "memory")
#define VM0() asm volatile("s_waitcnt vmcnt(0)" ::: "memory")

// Stage one half-tile (128 rows x 64 cols bf16 = 16 KiB) linearly into LDS,
// with the global SOURCE pre-swizzled so that LDS physical layout matches
// the XOR-swizzled read path (rule #21: both-sides-or-neither).
__device__ __forceinline__ void stage_half(const char* gsrc0, size_t rstride,
                                           u16* lhalf, int wv, int lane) {
  #pragma unroll
  for (int j = 0; j < 2; ++j) {
    const int o   = j*8192 + wv*1024 + lane*16;   // dest byte offset (linear)
    const int row = o >> 7;                        // 128 B per row
    const int cb  = (o & 127) ^ ((row & 7) << 4);  // inverse-swizzled src col
    gl2lds16((const u16*)(gsrc0 + (size_t)row*rstride + cb),
             (u16*)((char*)lhalf + j*8192 + wv*1024));
  }
}

// Swizzled ds_read_b128 of one MFMA fragment. kb = byte col (mult of 16).
__device__ __forceinline__ short8 ldsfrag(const u16* slot, int row, int kb) {
  return *(const short8*)((const char*)slot + row*128 + (kb ^ ((row & 7) << 4)));
}

#define QUAD(AH, NB)                                                          \
  _Pragma("unroll")                                                           \
  for (int i = 0; i < 4; ++i)                                                 \
    _Pragma("unroll")                                                         \
    for (int nf = 0; nf < 2; ++nf)                                            \
      _Pragma("unroll")                                                       \
      for (int ks = 0; ks < 2; ++ks)                                          \
        acc[(AH)*4 + i][(NB)*2 + nf] =                                        \
            MFMA16(af[AH][i][ks], bf[nf][ks], acc[(AH)*4 + i][(NB)*2 + nf]);

#define RD_AF(H, SLOT)                                                        \
  _Pragma("unroll")                                                           \
  for (int i = 0; i < 4; ++i)                                                 \
    _Pragma("unroll")                                                         \
    for (int ks = 0; ks < 2; ++ks)                                            \
      af[H][i][ks] = ldsfrag((SLOT), wm*128 + (H)*64 + i*16 + r16, ks*64 + q4*16);

#define RD_BF(SLOT, OFF)                                                      \
  _Pragma("unroll")                                                           \
  for (int nf = 0; nf < 2; ++nf)                                              \
    _Pragma("unroll")                                                         \
    for (int ks = 0; ks < 2; ++ks)                                            \
      bf[nf][ks] = ldsfrag((SLOT), wn*64 + (OFF) + nf*16 + r16, ks*64 + q4*16);

template <int MODE>
__global__ __launch_bounds__(512, 2)
void gemm_bt(const u16* __restrict__ A, const u16* __restrict__ Bw,
             const float* __restrict__ bias, int K, int Nt, int swz,
             u16* __restrict__ outB, u16* __restrict__ QKV, long long projStride) {
  __shared__ __align__(16) u16 SH[65536];       // 128 KiB, manually partitioned
  u16* const As0 = SH;                          // 32 KiB each
  u16* const As1 = SH + 16384;
  u16* const Bs0 = SH + 32768;
  u16* const Bs1 = SH + 49152;
  const int tid  = threadIdx.x;
  const int lane = tid & 63;
  const int wv   = tid >> 6;          // 0..7
  const int wm   = wv >> 2;           // 0..1  (128-row half)
  const int wn   = wv & 3;            // 0..3  (64-col strip)
  const int id   = blockIdx.x;
  int mt, nt2;
  if (swz) { mt = (id / (8*Nt))*8 + (id & 7); nt2 = (id >> 3) % Nt; }
  else     { mt = id / Nt;                    nt2 = id % Nt; }
  const int m0 = mt * 256;
  const int n0 = nt2 * 256;
  const int KT = K >> 6;              // K-tiles of 64; K in {512,1024} -> KT even
  const int NI = KT >> 1;             // iterations of 2 K-tiles

  const char* Abase = (const char*)(A  + (size_t)m0*K);
  const char* Bbase = (const char*)(Bw + (size_t)n0*K);
  const size_t rs = (size_t)K * 2;

  const int r16 = lane & 15;
  const int q4  = lane >> 4;

  const f32x4 fz = {0.f, 0.f, 0.f, 0.f};
  f32x4 acc[8][4];
  #pragma unroll
  for (int i = 0; i < 8; ++i)
    #pragma unroll
    for (int j = 0; j < 4; ++j) acc[i][j] = fz;

  short8 af[2][4][2];
  short8 bf[2][2];

  // ---- prologue: stage t0.A, t0.B, t1.A (6 half-tiles = 12 loads); VM4
  //      retires t0.A + t0.B, leaves t1.A flying.
  stage_half(Abase,              rs, As0,            wv, lane);
  stage_half(Abase + 128*rs,     rs, As0 + 128*64,   wv, lane);
  stage_half(Bbase,              rs, Bs0,            wv, lane);
  stage_half(Bbase + 128*rs,     rs, Bs0 + 128*64,   wv, lane);
  stage_half(Abase + 128,        rs, As1,            wv, lane);
  stage_half(Abase + 128*rs + 128, rs, As1 + 128*64, wv, lane);
  VM4();
  BAR();

  for (int it = 0; it < NI; ++it) {
    const int ta = it*2;                         // even tile -> buf0
    const bool m2 = (ta + 2 < KT);               // next-iter tiles exist
    const char* gBb  = Bbase + (size_t)(ta+1)*128;   // b.B  (this iter)
    const char* gAa2 = Abase + (size_t)(ta+2)*128;   // a'.A
    const char* gBa2 = Bbase + (size_t)(ta+2)*128;   // a'.B
    const char* gAb1 = Abase + (size_t)(ta+3)*128;   // b'.A

    // ---- ph1: rd af0/bf-lo (buf0) ; stage b.B.h0 ; MFMA (m0,n0) of tile a
    RD_AF(0, As0); RD_BF(Bs0, 0);
    asm volatile("s_waitcnt lgkmcnt(8)" ::: "memory");
    stage_half(gBb, rs, Bs1, wv, lane);
    BAR(); LGKM0();
    __builtin_amdgcn_s_setprio(1); QUAD(0, 0); __builtin_amdgcn_s_setprio(0);
    BAR();

    // ---- ph2: rd af1 ; stage b.B.h1 ; MFMA (m1,n0)
    RD_AF(1, As0);
    stage_half(gBb + 128*rs, rs, Bs1 + 128*64, wv, lane);
    BAR(); LGKM0();
    __builtin_amdgcn_s_setprio(1); QUAD(1, 0); __builtin_amdgcn_s_setprio(0);
    BAR();

    // ---- ph3: rd bf-hi ; stage a'.A.h0 ; MFMA (m1,n1)
    RD_BF(Bs0, 32);
    if (m2) stage_half(gAa2, rs, As0, wv, lane);
    BAR(); LGKM0();
    __builtin_amdgcn_s_setprio(1); QUAD(1, 1); __builtin_amdgcn_s_setprio(0);
    BAR();

    // ---- ph4: stage a'.A.h1 ; MFMA (m0,n1) ; counted vmcnt (retires b.B +
    //          prev-b'A; leaves a'A flying). Final iter: drain.
    if (m2) stage_half(gAa2 + 128*rs, rs, As0 + 128*64, wv, lane);
    BAR();
    __builtin_amdgcn_s_setprio(1); QUAD(0, 1); __builtin_amdgcn_s_setprio(0);
    if (m2) { VM4(); } else { VM0(); }
    BAR();

    // ---- ph5: rd af0/bf-lo (buf1) ; stage a'.B.h0 ; MFMA (m0,n0) of tile b
    RD_AF(0, As1); RD_BF(Bs1, 0);
    asm volatile("s_waitcnt lgkmcnt(8)" ::: "memory");
    if (m2) stage_half(gBa2, rs, Bs0, wv, lane);
    BAR(); LGKM0();
    __builtin_amdgcn_s_setprio(1); QUAD(0, 0); __builtin_amdgcn_s_setprio(0);
    BAR();

    // ---- ph6: rd af1 ; stage a'.B.h1 ; MFMA (m1,n0)
    RD_AF(1, As1);
    if (m2) stage_half(gBa2 + 128*rs, rs, Bs0 + 128*64, wv, lane);
    BAR(); LGKM0();
    __builtin_amdgcn_s_setprio(1); QUAD(1, 0); __builtin_amdgcn_s_setprio(0);
    BAR();

    // ---- ph7: rd bf-hi ; stage b'.A.h0 ; MFMA (m1,n1)
    RD_BF(Bs1, 32);
    if (m2) stage_half(gAb1, rs, As1, wv, lane);
    BAR(); LGKM0();
    __builtin_amdgcn_s_setprio(1); QUAD(1, 1); __builtin_amdgcn_s_setprio(0);
    BAR();

    // ---- ph8: stage b'.A.h1 ; MFMA (m0,n1) ; counted vmcnt (retires a'A +
    //          a'B, needed next ph1; leaves b'A flying).
    if (m2) stage_half(gAb1 + 128*rs, rs, As1 + 128*64, wv, lane);
    BAR();
    __builtin_amdgcn_s_setprio(1); QUAD(0, 1); __builtin_amdgcn_s_setprio(0);
    if (m2) VM4();
    BAR();
  }

  // ---- epilogue: LDS-retranspose coalesced stores ----
  VM0();                                         // safety: all staging retired
  __syncthreads();
  {
    u16* const L = SH;
    const int LROW = 272;
    #pragma unroll
    for (int h = 0; h < 2; ++h) {
      if (h == 1) __syncthreads();               // protect L reuse across passes
      if (wm == h) {
        #pragma unroll
        for (int nf = 0; nf < 4; ++nf) {
          const int col_l = wn*64 + nf*16 + r16;
          const float bvs = (MODE == 0) ? 0.f : bias[n0 + col_l];
          #pragma unroll
          for (int mi = 0; mi < 8; ++mi) {
            const int row_l = mi*16 + q4*4;
            #pragma unroll
            for (int r = 0; r < 4; ++r) {
              float v = acc[mi][nf][r];
              if (MODE == 0)      v = clampf(v, -1.f, 1.f);
              else if (MODE == 1) v = clampf(v + bvs, -3.f, 3.f);
              else if (MODE == 2) v = fmaxf(clampf(v + bvs, -2.f, 2.f), 0.f);
              else                v = clampf(v + bvs, -2.f, 2.f);
              L[(row_l + r)*LROW + col_l] = f2bf(v);
            }
          }
        }
      }
      __syncthreads();
      #pragma unroll
      for (int k = 0; k < 8; ++k) {
        const int ch   = wv*512 + k*64 + lane;   // 16B chunk id (0..4095)
        const int row  = ch >> 5;                // 32 chunks per 256-col row
        const int colu = (ch & 31) * 8;          // u16 col
        short8 d = *(const short8*)&L[row*LROW + colu];
        const int rowg = m0 + h*128 + row;
        const int cg   = n0 + colu;
        if (MODE == 0) {
          const unsigned proj = (unsigned)cg >> 9;
          const unsigned hh   = ((unsigned)cg >> 6) & 7u;
          const unsigned dk   = (unsigned)cg & 63u;
          const int b = rowg / 200;
          const int s = rowg - b*200;
          *(short8*)&QKV[(size_t)proj*projStride + (size_t)hh*12800
                         + (size_t)b*102400 + (size_t)s*64 + dk] = d;
        } else {
          const int N = (MODE == 2) ? 1024 : 512;
          *(short8*)&outB[(size_t)rowg*N + cg] = d;
        }
      }
    }
  }
}

// ---------------------------------------------------------------- fused attention
// 8 waves / 512 threads: 2 q-blocks of 128 rows. LDS ~70.7 KB -> 2 blocks/CU,
// 16 waves/CU. V-transpose staging conflict-free (lanes write consecutive s).
__global__ __launch_bounds__(512)
void attn_kernel(const u16* __restrict__ Q, const u16* __restrict__ K,
                 const u16* __restrict__ V, const int* __restrict__ iseq,
                 u16* __restrict__ x2b) {
  __shared__ __align__(16) u16 Ks[208*72];
  __shared__ __align__(16) u16 Vs[64*232];
  __shared__ __align__(16) u16 Ps[8][16*40];
  __shared__ float msk[208];

  const int tid = threadIdx.x, lane = tid & 63, wv = tid >> 6;
  const unsigned bid = blockIdx.x;
  const int h = bid & 7;
  const int b = bid >> 3;
  const size_t bh = (size_t)b*8 + h;
  const u16* Kg = K + bh*12800;
  const u16* Vg = V + bh*12800;
  const u16* Qg = Q + bh*12800;

  for (int c = tid; c < 3200; c += 512) {       // K -> Ks[key][dk]
    int row = c >> 4, q = c & 15;
    *(ushort4*)&Ks[row*72 + q*4] = *(const ushort4*)&Kg[row*64 + q*4];
  }
  // V -> Vs[dk][s] transpose: wave w owns d-quads {2w, 2w+1}; lanes walk
  // consecutive s -> contiguous u16 LDS stores (no bank conflicts).
  {
    const int quad = wv*2 + (lane >> 5);        // 0..15
    const int sl   = lane & 31;
    #pragma unroll
    for (int it = 0; it < 7; ++it) {
      const int s = sl + it*32;
      if (s < 200) {
        ushort4 v4 = *(const ushort4*)&Vg[s*64 + quad*4];
        Vs[(quad*4+0)*232 + s] = v4.x;
        Vs[(quad*4+1)*232 + s] = v4.y;
        Vs[(quad*4+2)*232 + s] = v4.z;
        Vs[(quad*4+3)*232 + s] = v4.w;
      }
    }
  }
  for (int c = tid; c < 2048; c += 512) {
    int dk = c >> 5, s2 = 200 + (c & 31);
    Vs[dk*232 + s2] = 0;
  }
  for (int t = tid; t < 208; t += 512)
    msk[t] = (t < 200 && iseq[b*200 + t] != 0) ? 1.f : 0.f;
  __syncthreads();

  const int colk = lane & 15;
  const int fk8 = (lane >> 4) * 8;
  const int prow = (lane >> 4) * 4;
  const f32x4 fz = {0.f,0.f,0.f,0.f};

  for (int qb = 0; qb < 2; ++qb) {
    const int qrow = qb*128 + wv*16 + (lane & 15);
    const int qsrc = qrow < 200 ? qrow : 199;
    short8 qa0 = *(const short8*)&Qg[(size_t)qsrc*64 + fk8];
    short8 qa1 = *(const short8*)&Qg[(size_t)qsrc*64 + 32 + fk8];
    f32x4 oacc[4];
    #pragma unroll
    for (int nt = 0; nt < 4; ++nt) oacc[nt] = fz;
    float rs[4] = {0.f,0.f,0.f,0.f};

    for (int kt2 = 0; kt2 < 7; ++kt2) {
      #pragma unroll
      for (int half = 0; half < 2; ++half) {
        const int stile = kt2*2 + half;
        if (stile < 13) {
          const int key = stile*16 + colk;
          short8 kb0 = *(const short8*)&Ks[key*72 + fk8];
          short8 kb1 = *(const short8*)&Ks[key*72 + 32 + fk8];
          f32x4 sc = fz;
          __builtin_amdgcn_s_setprio(1);
          sc = MFMA16(qa0, kb0, sc);
          sc = MFMA16(qa1, kb1, sc);
          __builtin_amdgcn_s_setprio(0);
          const float mk = msk[key];
          #pragma unroll
          for (int r = 0; r < 4; ++r) {
            float p = __expf(clampf(sc[r]*2.5f, -3.f, 3.f)) * mk;
            rs[r] += p;
            Ps[wv][(prow + r)*40 + half*16 + colk] = f2bf(p);
          }
        } else {
          #pragma unroll
          for (int r = 0; r < 4; ++r)
            Ps[wv][(prow + r)*40 + half*16 + colk] = 0;
        }
      }
      asm volatile("s_waitcnt lgkmcnt(0)" ::: "memory");
      short8 pa = *(const short8*)&Ps[wv][(lane & 15)*40 + fk8];
      const int kb32 = kt2*32;
      __builtin_amdgcn_s_setprio(1);
      #pragma unroll
      for (int nt = 0; nt < 4; ++nt) {
        short8 vb = *(const short8*)&Vs[(nt*16 + colk)*232 + kb32 + fk8];
        oacc[nt] = MFMA16(pa, vb, oacc[nt]);
      }
      __builtin_amdgcn_s_setprio(0);
      asm volatile("s_waitcnt lgkmcnt(0)" ::: "memory");
    }

    #pragma unroll
    for (int m = 1; m <= 8; m <<= 1)
      #pragma unroll
      for (int r = 0; r < 4; ++r) rs[r] += __shfl_xor(rs[r], m);

    const int srow = qb*128 + wv*16 + prow;
    #pragma unroll
    for (int r = 0; r < 4; ++r) {
      const int s = srow + r;
      if (s < 200) {
        const float inv = rs[r] > 0.f ? 1.f/rs[r] : 0.f;
        const size_t base = ((size_t)b*200 + s)*512 + h*64;
        #pragma unroll
        for (int nt = 0; nt < 4; ++nt)
          x2b[base + nt*16 + colk] = f2bf(oacc[nt][r] * inv);
      }
    }
  }
}

// ---------------------------------------------------------------- LN1 (double): xn = LN(x + LN(x+x2)); x from xb (bf16)
__global__ __launch_bounds__(256)
void ln1_kernel(const u16* __restrict__ xb, const u16* __restrict__ x2b,
                const float* __restrict__ g, const float* __restrict__ bb,
                u16* __restrict__ xnb) {
  const int lane = threadIdx.x & 63, wv = threadIdx.x >> 6;
  const size_t t = (size_t)blockIdx.x*4 + wv;
  const int c0 = lane*4, c1 = 256 + lane*4;
  ushort4 xa = *(const ushort4*)&xb[t*512 + c0];
  ushort4 xc = *(const ushort4*)&xb[t*512 + c1];
  ushort4 ha = *(const ushort4*)&x2b[t*512 + c0];
  ushort4 hc = *(const ushort4*)&x2b[t*512 + c1];
  float xv[8] = {bf2f(xa.x),bf2f(xa.y),bf2f(xa.z),bf2f(xa.w),
                 bf2f(xc.x),bf2f(xc.y),bf2f(xc.z),bf2f(xc.w)};
  float tv[8] = {xv[0]+bf2f(ha.x), xv[1]+bf2f(ha.y), xv[2]+bf2f(ha.z), xv[3]+bf2f(ha.w),
                 xv[4]+bf2f(hc.x), xv[5]+bf2f(hc.y), xv[6]+bf2f(hc.z), xv[7]+bf2f(hc.w)};
  float s1 = 0.f, s2 = 0.f;
  #pragma unroll
  for (int i = 0; i < 8; ++i) { s1 += tv[i]; s2 += tv[i]*tv[i]; }
  #pragma unroll
  for (int m = 1; m <= 32; m <<= 1) { s1 += __shfl_xor(s1, m); s2 += __shfl_xor(s2, m); }
  float mean = s1*(1.f/512.f);
  float inv = 1.f/sqrtf(s2*(1.f/512.f) - mean*mean + 1e-6f);
  float4 ga = *(const float4*)(g + c0), gc = *(const float4*)(g + c1);
  float4 ba = *(const float4*)(bb + c0), bc = *(const float4*)(bb + c1);
  float gv[8] = {ga.x,ga.y,ga.z,ga.w, gc.x,gc.y,gc.z,gc.w};
  float bv[8] = {ba.x,ba.y,ba.z,ba.w, bc.x,bc.y,bc.z,bc.w};
  float uv[8]; float s3 = 0.f, s4 = 0.f;
  #pragma unroll
  for (int i = 0; i < 8; ++i) {
    float sa = (tv[i]-mean)*inv*gv[i] + bv[i];
    uv[i] = xv[i] + sa;
    s3 += uv[i]; s4 += uv[i]*uv[i];
  }
  #pragma unroll
  for (int m = 1; m <= 32; m <<= 1) { s3 += __shfl_xor(s3, m); s4 += __shfl_xor(s4, m); }
  float mean2 = s3*(1.f/512.f);
  float inv2 = 1.f/sqrtf(s4*(1.f/512.f) - mean2*mean2 + 1e-6f);
  ushort4 o0, o1;
  o0.x = f2bf((uv[0]-mean2)*inv2*gv[0] + bv[0]);
  o0.y = f2bf((uv[1]-mean2)*inv2*gv[1] + bv[1]);
  o0.z = f2bf((uv[2]-mean2)*inv2*gv[2] + bv[2]);
  o0.w = f2bf((uv[3]-mean2)*inv2*gv[3] + bv[3]);
  o1.x = f2bf((uv[4]-mean2)*inv2*gv[4] + bv[4]);
  o1.y = f2bf((uv[5]-mean2)*inv2*gv[5] + bv[5]);
  o1.z = f2bf((uv[6]-mean2)*inv2*gv[6] + bv[6]);
  o1.w = f2bf((uv[7]-mean2)*inv2*gv[7] + bv[7]);
  *(ushort4*)&xnb[t*512 + c0] = o0;
  *(ushort4*)&xnb[t*512 + c1] = o1;
}

// ---------------------------------------------------------------- LN2 (double) + masked partials — barrier-free
__global__ __launch_bounds__(256)
void ln2_kernel(const u16* __restrict__ xnb, const u16* __restrict__ f2b,
                const float* __restrict__ g, const float* __restrict__ bb,
                const int* __restrict__ iseq, float* __restrict__ seq_acc) {
  const int tid = threadIdx.x, lane = tid & 63, wv = tid >> 6;
  const int q = blockIdx.x, bl = blockIdx.y;
  const int c8 = lane*8;
  float gv[8], bv[8];
  *(float4*)&gv[0] = *(const float4*)(g + c8);
  *(float4*)&gv[4] = *(const float4*)(g + c8 + 4);
  *(float4*)&bv[0] = *(const float4*)(bb + c8);
  *(float4*)&bv[4] = *(const float4*)(bb + c8 + 4);
  float acc[8] = {};
  for (int i = wv; i < 50; i += 4) {
    const int s = q*50 + i;
    const size_t row = (size_t)bl*200 + s;
    short8 xh = *(const short8*)&xnb[row*512 + c8];
    short8 yh = *(const short8*)&f2b[row*512 + c8];
    float xv[8], tv[8];
    #pragma unroll
    for (int j = 0; j < 8; ++j) {
      xv[j] = bf2f((u16)xh[j]);
      tv[j] = xv[j] + bf2f((u16)yh[j]);
    }
    float s1 = 0.f, s2 = 0.f;
    #pragma unroll
    for (int j = 0; j < 8; ++j) { s1 += tv[j]; s2 += tv[j]*tv[j]; }
    #pragma unroll
    for (int m = 1; m <= 32; m <<= 1) { s1 += __shfl_xor(s1,m); s2 += __shfl_xor(s2,m); }
    float mean = s1*(1.f/512.f);
    float inv = 1.f/sqrtf(s2*(1.f/512.f) - mean*mean + 1e-6f);
    float uv[8]; float s3 = 0.f, s4 = 0.f;
    #pragma unroll
    for (int j = 0; j < 8; ++j) {
      uv[j] = xv[j] + (tv[j]-mean)*inv*gv[j] + bv[j];
      s3 += uv[j]; s4 += uv[j]*uv[j];
    }
    #pragma unroll
    for (int m = 1; m <= 32; m <<= 1) { s3 += __shfl_xor(s3,m); s4 += __shfl_xor(s4,m); }
    float mean2 = s3*(1.f/512.f);
    float inv2 = 1.f/sqrtf(s4*(1.f/512.f) - mean2*mean2 + 1e-6f);
    if (iseq[row] != 0) {
      #pragma unroll
      for (int j = 0; j < 8; ++j)
        acc[j] += clampf((uv[j]-mean2)*inv2*gv[j] + bv[j], -5.f, 5.f);
    }
  }
  float* dst = &seq_acc[(((size_t)bl*4 + q)*4 + wv)*512 + c8];
  *(float4*)&dst[0] = *(float4*)&acc[0];
  *(float4*)&dst[4] = *(float4*)&acc[4];
}

// ---------------------------------------------------------------- assemble user vector u (512 x 1152)
__global__ __launch_bounds__(256)
void build_u_kernel(const float* __restrict__ seq_acc, const float* __restrict__ cnt,
                    const float* __restrict__ uac, const float* __restrict__ uti,
                    const int* __restrict__ age, const int* __restrict__ gen,
                    const int* __restrict__ cms,
                    const float* __restrict__ age_tab, const float* __restrict__ gen_tab,
                    const float* __restrict__ cms_tab,
                    const float* __restrict__ ctr_w, const float* __restrict__ ctr_b,
                    const float* __restrict__ ti_w, const float* __restrict__ ti_b,
                    float* __restrict__ u) {
  const int b = blockIdx.x;
  for (int j = threadIdx.x; j < 1152; j += 256) {
    float v;
    if (j < 512) {
      float ssum = 0.f;
      #pragma unroll
      for (int p = 0; p < 16; ++p) ssum += seq_acc[((size_t)b*16 + p)*512 + j];
      v = clampf(ssum / (cnt[b] + 1e-8f), -5.f, 5.f);
    }
    else if (j < 640)  { int e = j-512;  v = uac[b]*ctr_w[e] + ctr_b[e]; }
    else if (j < 768)  { int e = j-640;  v = uti[b]*ti_w[e] + ti_b[e]; }
    else if (j < 896)  { int e = j-768;  v = age_tab[age[b]*128 + e]; }
    else if (j < 1024) { int e = j-896;  v = gen_tab[gen[b]*128 + e]; }
    else               { int e = j-1024; v = cms_tab[cms[b]*128 + e]; }
    u[(size_t)b*1152 + j] = v;
  }
}

// ---------------------------------------------------------------- mlp1
__global__ __launch_bounds__(256)
void mlp1_kernel(const float* __restrict__ u, const float* __restrict__ w,
                 const float* __restrict__ bias, float* __restrict__ h1) {
  __shared__ __align__(16) float As[64][36];
  __shared__ __align__(16) float Wt[32][68];
  const int tid = threadIdx.x;
  const int m0 = blockIdx.x*64, n0 = blockIdx.y*64;
  const int tm = tid >> 4, tn = tid & 15;
  float acc[4][4] = {};
  for (int k0 = 0; k0 < 1152; k0 += 32) {
    for (int c = tid; c < 512; c += 256) {
      int row = c >> 3, q = c & 7;
      *(float4*)&As[row][q*4] = *(const float4*)&u[(size_t)(m0+row)*1152 + k0 + q*4];
      float4 wv4 = *(const float4*)&w[(size_t)(n0+row)*1152 + k0 + q*4];
      Wt[q*4+0][row] = wv4.x; Wt[q*4+1][row] = wv4.y;
      Wt[q*4+2][row] = wv4.z; Wt[q*4+3][row] = wv4.w;
    }
    __syncthreads();
    #pragma unroll
    for (int kk = 0; kk < 32; ++kk) {
      float av[4], bw[4];
      #pragma unroll
      for (int i = 0; i < 4; ++i) av[i] = As[tm*4+i][kk];
      #pragma unroll
      for (int j = 0; j < 4; ++j) bw[j] = Wt[kk][tn*4+j];
      #pragma unroll
      for (int i = 0; i < 4; ++i)
        #pragma unroll
        for (int j = 0; j < 4; ++j) acc[i][j] += av[i]*bw[j];
    }
    __syncthreads();
  }
  #pragma unroll
  for (int i = 0; i < 4; ++i)
    #pragma unroll
    for (int j = 0; j < 4; ++j) {
      int n = n0 + tn*4 + j;
      h1[(size_t)(m0 + tm*4 + i)*1024 + n] = fmaxf(acc[i][j] + bias[n], 0.f);
    }
}

// ---------------------------------------------------------------- mlp2
__global__ __launch_bounds__(256)
void mlp2_kernel(const float* __restrict__ h1, const float* __restrict__ w,
                 const float* __restrict__ bias, float* __restrict__ out) {
  const int tid = threadIdx.x;
  const int m = blockIdx.x*4 + (tid >> 6);
  const int n = tid & 63;
  const float4* hr = (const float4*)(h1 + (size_t)m*1024);
  const float4* wr = (const float4*)(w + (size_t)n*1024);
  float acc = 0.f;
  for (int k4 = 0; k4 < 256; ++k4) {
    float4 a = hr[k4], bw = wr[k4];
    acc += a.x*bw.x + a.y*bw.y + a.z*bw.z + a.w*bw.w;
  }
  out[(size_t)m*64 + n] = acc + bias[n];
}

// ================================================================ launch
extern "C" void kernel_launch(void* const* d_in, const int* in_sizes, int n_in,
                              void* d_out, int out_size, void* d_ws, size_t ws_size,
                              hipStream_t stream) {
  (void)in_sizes; (void)n_in; (void)out_size;
  const int*   item_seq   = (const int*)d_in[0];
  const float* uac        = (const float*)d_in[1];
  const float* uti        = (const float*)d_in[2];
  const int*   age        = (const int*)d_in[3];
  const int*   gen        = (const int*)d_in[4];
  const int*   cms        = (const int*)d_in[5];
  const float* emb        = (const float*)d_in[6];
  const float* in_proj_w  = (const float*)d_in[7];
  const float* out_proj_w = (const float*)d_in[8];
  const float* out_proj_b = (const float*)d_in[9];
  const float* ln1_g = (const float*)d_in[10];
  const float* ln1_b = (const float*)d_in[11];
  const float* ln2_g = (const float*)d_in[12];
  const float* ln2_b = (const float*)d_in[13];
  const float* lin1_w = (const float*)d_in[14];
  const float* lin1_b = (const float*)d_in[15];
  const float* lin2_w = (const float*)d_in[16];
  const float* lin2_b = (const float*)d_in[17];
  const float* age_tab = (const float*)d_in[18];
  const float* gen_tab = (const float*)d_in[19];
  const float* cms_tab = (const float*)d_in[20];
  const float* ctr_w = (const float*)d_in[21];
  const float* ctr_b = (const float*)d_in[22];
  const float* ti_w  = (const float*)d_in[23];
  const float* ti_b  = (const float*)d_in[24];
  const float* mlp1_w = (const float*)d_in[25];
  const float* mlp1_b = (const float*)d_in[26];
  const float* mlp2_w = (const float*)d_in[27];
  const float* mlp2_b = (const float*)d_in[28];

  // ---- adaptive chunking: 5 regions of CB*200*512*2 B each + tail ----
  const long long TAILB = 25430016LL;
  int CB = 32;
  if      ((long long)ws_size >= 512LL*1024000 + TAILB) CB = 512;  // 549.7 MB (ws ~819 MB)
  else if ((long long)ws_size >= 128LL*1024000 + TAILB) CB = 128;
  else if ((long long)ws_size >=  64LL*1024000 + TAILB) CB = 64;
  const long long R = (long long)CB * 204800;

  char* ws = (char*)d_ws;
  u16* xb   = (u16*)(ws);            // region 0: embed bf16 (live through ln1)
  u16* x2b  = (u16*)(ws + R);        // region 1: attn out
  u16* Qb   = (u16*)(ws + 2*R);      // region 2: Q; later x2o
  u16* Kb   = (u16*)(ws + 3*R);      // region 3: K; later xnb
  u16* Vrb  = (u16*)(ws + 4*R);      // region 4: V; later f2b
  u16* x2o  = Qb;
  u16* xnb  = Kb;
  u16* f2b  = Vrb;
  u16* hbuf = (u16*)(ws);            // regions 0-1 (xb,x2b dead after ln1)
  char* tail = ws + 5*R;
  float* seq_acc = (float*)(tail);              // 16,777,216  [B][16][512]
  float* cnt     = (float*)(tail + 16777216);   // 2,048
  float* u       = (float*)(tail + 16779264);   // 2,359,296
  float* h1      = (float*)(tail + 19138560);   // 2,097,152
  u16*   wqkv    = (u16*)(tail + 21235712);     // 1,572,864
  u16*   wout    = (u16*)(tail + 22808576);     // 524,288
  u16*   wl1     = (u16*)(tail + 23332864);     // 1,048,576
  u16*   wl2     = (u16*)(tail + 24381440);     // 1,048,576 -> 25,430,016

  cvt_bf16_kernel<<<768, 256, 0, stream>>>(in_proj_w, wqkv, 1536*512);
  cvt_bf16_kernel<<<256, 256, 0, stream>>>(out_proj_w, wout, 512*512);
  cvt_bf16_kernel<<<512, 256, 0, stream>>>(lin1_w, wl1, 1024*512);
  cvt_bf16_kernel<<<512, 256, 0, stream>>>(lin2_w, wl2, 512*1024);
  cnt_kernel<<<512, 256, 0, stream>>>(item_seq, cnt);

  const int nch = 512 / CB;
  const int Mc  = CB * 200;
  const int Mt  = Mc / 256;                    // 256-row tiles
  const int swz = (Mt % 8 == 0) ? 1 : 0;
  const long long projStride = (long long)CB * 102400;
  for (int ch = 0; ch < nch; ++ch) {
    const int* iseq = item_seq + (size_t)ch*CB*200;
    embed_kernel<<<Mc/2, 256, 0, stream>>>(iseq, emb, xb);
    gemm_bt<0><<<Mt*6, 512, 0, stream>>>(xb, wqkv, nullptr, 512, 6, swz,
                                         nullptr, Qb, projStride);
    attn_kernel<<<CB*8, 512, 0, stream>>>(Qb, Kb, Vrb, iseq, x2b);
    gemm_bt<1><<<Mt*2, 512, 0, stream>>>(x2b, wout, out_proj_b, 512, 2, swz,
                                         x2o, nullptr, 0);
    ln1_kernel<<<Mc/4, 256, 0, stream>>>(xb, x2o, ln1_g, ln1_b, xnb);
    gemm_bt<2><<<Mt*4, 512, 0, stream>>>(xnb, wl1, lin1_b, 512, 4, swz,
                                         hbuf, nullptr, 0);
    gemm_bt<3><<<Mt*2, 512, 0, stream>>>(hbuf, wl2, lin2_b, 1024, 2, swz,
                                         f2b, nullptr, 0);
    ln2_kernel<<<dim3(4, CB), 256, 0, stream>>>(xnb, f2b, ln2_g, ln2_b, iseq,
                                                seq_acc + (size_t)ch*CB*8192);
  }

  build_u_kernel<<<512, 256, 0, stream>>>(seq_acc, cnt, uac, uti, age, gen, cms,
                                          age_tab, gen_tab, cms_tab,
                                          ctr_w, ctr_b, ti_w, ti_b, u);
  mlp1_kernel<<<dim3(8, 16), 256, 0, stream>>>(u, mlp1_w, mlp1_b, h1);
  mlp2_kernel<<<128, 256, 0, stream>>>(h1, mlp2_w, mlp2_b, (float*)d_out);
}

// Round 9
// 1374.467 us; speedup vs baseline: 1.1995x; 1.0090x over previous
//
#include <hip/hip_runtime.h>
#include <hip/hip_bf16.h>
#include <stdint.h>

typedef __attribute__((ext_vector_type(8))) short short8;
typedef __attribute__((ext_vector_type(4))) float f32x4;
typedef unsigned short u16;

#define MFMA16(a,b,c) __builtin_amdgcn_mfma_f32_16x16x32_bf16((a),(b),(c),0,0,0)

__device__ __forceinline__ u16 f2bf(float f) {           // RNE f32->bf16
  unsigned int u = __float_as_uint(f);
  return (u16)((u + 0x7FFFu + ((u >> 16) & 1u)) >> 16);
}
__device__ __forceinline__ float bf2f(u16 h) {
  return __uint_as_float(((unsigned int)h) << 16);
}
__device__ __forceinline__ float clampf(float v, float lo, float hi) {
  return fminf(fmaxf(v, lo), hi);
}
__device__ __forceinline__ void gl2lds16(const u16* g, u16* l) {
  __builtin_amdgcn_global_load_lds(
      (const __attribute__((address_space(1))) unsigned int*)g,
      (__attribute__((address_space(3))) unsigned int*)(uintptr_t)l,
      16, 0, 0);
}

// ---------------------------------------------------------------- convert (4 arrays, one launch)
__global__ __launch_bounds__(256) void cvt_all_kernel(
    const float* __restrict__ s0, u16* __restrict__ d0, int n0,
    const float* __restrict__ s1, u16* __restrict__ d1, int n1,
    const float* __restrict__ s2, u16* __restrict__ d2, int n2,
    const float* __restrict__ s3, u16* __restrict__ d3, int n3) {
  const int n = n0 + n1 + n2 + n3;
  for (int i = blockIdx.x*256 + threadIdx.x; i < n; i += gridDim.x*256) {
    int j = i;
    const float* s; u16* d;
    if (j < n0)              { s = s0; d = d0; }
    else if ((j -= n0) < n1) { s = s1; d = d1; }
    else if ((j -= n1) < n2) { s = s2; d = d2; }
    else                     { j -= n2; s = s3; d = d3; }
    d[j] = f2bf(s[j]);
  }
}

// ---------------------------------------------------------------- embed
__global__ __launch_bounds__(256) void embed_kernel(
    const int* __restrict__ iseq, const float* __restrict__ emb,
    u16* __restrict__ xb) {
  int gid = blockIdx.x*256 + threadIdx.x;
  int m = gid >> 7;
  int c = (gid & 127) * 4;
  int item = iseq[m];
  float4 e = *(const float4*)&emb[(size_t)item*512 + c];
  ushort4 hb;
  hb.x = f2bf(clampf(e.x*0.5f, -1.f, 1.f));
  hb.y = f2bf(clampf(e.y*0.5f, -1.f, 1.f));
  hb.z = f2bf(clampf(e.z*0.5f, -1.f, 1.f));
  hb.w = f2bf(clampf(e.w*0.5f, -1.f, 1.f));
  *(ushort4*)&xb[(size_t)m*512 + c] = hb;
}

// ---------------------------------------------------------------- valid count per batch
__global__ __launch_bounds__(256) void cnt_kernel(
    const int* __restrict__ item_seq, float* __restrict__ cnt) {
  __shared__ int sred[4];
  int b = blockIdx.x, tid = threadIdx.x;
  int lane = tid & 63, wv = tid >> 6;
  int c = 0;
  if (tid < 200) c = (item_seq[b*200 + tid] != 0) ? 1 : 0;
  #pragma unroll
  for (int m = 1; m <= 32; m <<= 1) c += __shfl_xor(c, m);
  if (lane == 0) sred[wv] = c;
  __syncthreads();
  if (tid == 0) cnt[b] = (float)(sred[0]+sred[1]+sred[2]+sred[3]);
}

// ---------------------------------------------------------------- GEMM  C = A @ W^T
// 256x256 tile, BK=64, 8 waves (2M x 4N), double-buffered 128 KiB LDS.
// m201 8-phase sandwich, vmcnt only at ph4/ph8 (round-8 structure, kept).
// Structural plateau for this shape (K=512, L3-resident A): ~685 TF across
// 5 schedule variants — accepted. Epilogue: LDS-retranspose coalesced stores.
// MODE 0: QKV scatter; 1: out_proj; 2: lin1+relu; 3: lin2.
#define BAR() asm volatile("s_barrier" ::: "memory")
#define LGKM0() do { asm volatile("s_waitcnt lgkmcnt(0)" ::: "memory"); \
                     __builtin_amdgcn_sched_barrier(0); } while (0)
#define VM4() asm volatile("s_waitcnt vmcnt(4)" ::: "memory")
#define VM0() asm volatile("s_waitcnt vmcnt(0)" ::: "memory")

// Stage one half-tile (128 rows x 64 cols bf16 = 16 KiB) linearly into LDS,
// with the global SOURCE pre-swizzled so that LDS physical layout matches
// the XOR-swizzled read path (rule #21: both-sides-or-neither).
__device__ __forceinline__ void stage_half(const char* gsrc0, size_t rstride,
                                           u16* lhalf, int wv, int lane) {
  #pragma unroll
  for (int j = 0; j < 2; ++j) {
    const int o   = j*8192 + wv*1024 + lane*16;   // dest byte offset (linear)
    const int row = o >> 7;                        // 128 B per row
    const int cb  = (o & 127) ^ ((row & 7) << 4);  // inverse-swizzled src col
    gl2lds16((const u16*)(gsrc0 + (size_t)row*rstride + cb),
             (u16*)((char*)lhalf + j*8192 + wv*1024));
  }
}

// Swizzled ds_read_b128 of one MFMA fragment. kb = byte col (mult of 16).
__device__ __forceinline__ short8 ldsfrag(const u16* slot, int row, int kb) {
  return *(const short8*)((const char*)slot + row*128 + (kb ^ ((row & 7) << 4)));
}

#define QUAD(AH, NB)                                                          \
  _Pragma("unroll")                                                           \
  for (int i = 0; i < 4; ++i)                                                 \
    _Pragma("unroll")                                                         \
    for (int nf = 0; nf < 2; ++nf)                                            \
      _Pragma("unroll")                                                       \
      for (int ks = 0; ks < 2; ++ks)                                          \
        acc[(AH)*4 + i][(NB)*2 + nf] =                                        \
            MFMA16(af[AH][i][ks], bf[nf][ks], acc[(AH)*4 + i][(NB)*2 + nf]);

#define RD_AF(H, SLOT)                                                        \
  _Pragma("unroll")                                                           \
  for (int i = 0; i < 4; ++i)                                                 \
    _Pragma("unroll")                                                         \
    for (int ks = 0; ks < 2; ++ks)                                            \
      af[H][i][ks] = ldsfrag((SLOT), wm*128 + (H)*64 + i*16 + r16, ks*64 + q4*16);

#define RD_BF(SLOT, OFF)                                                      \
  _Pragma("unroll")                                                           \
  for (int nf = 0; nf < 2; ++nf)                                              \
    _Pragma("unroll")                                                         \
    for (int ks = 0; ks < 2; ++ks)                                            \
      bf[nf][ks] = ldsfrag((SLOT), wn*64 + (OFF) + nf*16 + r16, ks*64 + q4*16);

template <int MODE>
__global__ __launch_bounds__(512, 2)
void gemm_bt(const u16* __restrict__ A, const u16* __restrict__ Bw,
             const float* __restrict__ bias, int K, int Nt, int swz,
             u16* __restrict__ outB, u16* __restrict__ QKV, long long projStride) {
  __shared__ __align__(16) u16 SH[65536];       // 128 KiB, manually partitioned
  u16* const As0 = SH;                          // 32 KiB each
  u16* const As1 = SH + 16384;
  u16* const Bs0 = SH + 32768;
  u16* const Bs1 = SH + 49152;
  const int tid  = threadIdx.x;
  const int lane = tid & 63;
  const int wv   = tid >> 6;          // 0..7
  const int wm   = wv >> 2;           // 0..1  (128-row half)
  const int wn   = wv & 3;            // 0..3  (64-col strip)
  const int id   = blockIdx.x;
  int mt, nt2;
  if (swz) { mt = (id / (8*Nt))*8 + (id & 7); nt2 = (id >> 3) % Nt; }
  else     { mt = id / Nt;                    nt2 = id % Nt; }
  const int m0 = mt * 256;
  const int n0 = nt2 * 256;
  const int KT = K >> 6;              // K-tiles of 64; K in {512,1024} -> KT even
  const int NI = KT >> 1;             // iterations of 2 K-tiles

  const char* Abase = (const char*)(A  + (size_t)m0*K);
  const char* Bbase = (const char*)(Bw + (size_t)n0*K);
  const size_t rs = (size_t)K * 2;

  const int r16 = lane & 15;
  const int q4  = lane >> 4;

  const f32x4 fz = {0.f, 0.f, 0.f, 0.f};
  f32x4 acc[8][4];
  #pragma unroll
  for (int i = 0; i < 8; ++i)
    #pragma unroll
    for (int j = 0; j < 4; ++j) acc[i][j] = fz;

  short8 af[2][4][2];
  short8 bf[2][2];

  // ---- prologue: stage t0.A, t0.B, t1.A (6 half-tiles = 12 loads); VM4
  //      retires t0.A + t0.B, leaves t1.A flying.
  stage_half(Abase,              rs, As0,            wv, lane);
  stage_half(Abase + 128*rs,     rs, As0 + 128*64,   wv, lane);
  stage_half(Bbase,              rs, Bs0,            wv, lane);
  stage_half(Bbase + 128*rs,     rs, Bs0 + 128*64,   wv, lane);
  stage_half(Abase + 128,        rs, As1,            wv, lane);
  stage_half(Abase + 128*rs + 128, rs, As1 + 128*64, wv, lane);
  VM4();
  BAR();

  for (int it = 0; it < NI; ++it) {
    const int ta = it*2;                         // even tile -> buf0
    const bool m2 = (ta + 2 < KT);               // next-iter tiles exist
    const char* gBb  = Bbase + (size_t)(ta+1)*128;   // b.B  (this iter)
    const char* gAa2 = Abase + (size_t)(ta+2)*128;   // a'.A
    const char* gBa2 = Bbase + (size_t)(ta+2)*128;   // a'.B
    const char* gAb1 = Abase + (size_t)(ta+3)*128;   // b'.A

    // ---- ph1: rd af0/bf-lo (buf0) ; stage b.B.h0 ; MFMA (m0,n0) of tile a
    RD_AF(0, As0); RD_BF(Bs0, 0);
    asm volatile("s_waitcnt lgkmcnt(8)" ::: "memory");
    stage_half(gBb, rs, Bs1, wv, lane);
    BAR(); LGKM0();
    __builtin_amdgcn_s_setprio(1); QUAD(0, 0); __builtin_amdgcn_s_setprio(0);
    BAR();

    // ---- ph2: rd af1 ; stage b.B.h1 ; MFMA (m1,n0)
    RD_AF(1, As0);
    stage_half(gBb + 128*rs, rs, Bs1 + 128*64, wv, lane);
    BAR(); LGKM0();
    __builtin_amdgcn_s_setprio(1); QUAD(1, 0); __builtin_amdgcn_s_setprio(0);
    BAR();

    // ---- ph3: rd bf-hi ; stage a'.A.h0 ; MFMA (m1,n1)
    RD_BF(Bs0, 32);
    if (m2) stage_half(gAa2, rs, As0, wv, lane);
    BAR(); LGKM0();
    __builtin_amdgcn_s_setprio(1); QUAD(1, 1); __builtin_amdgcn_s_setprio(0);
    BAR();

    // ---- ph4: stage a'.A.h1 ; MFMA (m0,n1) ; counted vmcnt (retires b.B +
    //          prev-b'A; leaves a'A flying). Final iter: drain.
    if (m2) stage_half(gAa2 + 128*rs, rs, As0 + 128*64, wv, lane);
    BAR();
    __builtin_amdgcn_s_setprio(1); QUAD(0, 1); __builtin_amdgcn_s_setprio(0);
    if (m2) { VM4(); } else { VM0(); }
    BAR();

    // ---- ph5: rd af0/bf-lo (buf1) ; stage a'.B.h0 ; MFMA (m0,n0) of tile b
    RD_AF(0, As1); RD_BF(Bs1, 0);
    asm volatile("s_waitcnt lgkmcnt(8)" ::: "memory");
    if (m2) stage_half(gBa2, rs, Bs0, wv, lane);
    BAR(); LGKM0();
    __builtin_amdgcn_s_setprio(1); QUAD(0, 0); __builtin_amdgcn_s_setprio(0);
    BAR();

    // ---- ph6: rd af1 ; stage a'.B.h1 ; MFMA (m1,n0)
    RD_AF(1, As1);
    if (m2) stage_half(gBa2 + 128*rs, rs, Bs0 + 128*64, wv, lane);
    BAR(); LGKM0();
    __builtin_amdgcn_s_setprio(1); QUAD(1, 0); __builtin_amdgcn_s_setprio(0);
    BAR();

    // ---- ph7: rd bf-hi ; stage b'.A.h0 ; MFMA (m1,n1)
    RD_BF(Bs1, 32);
    if (m2) stage_half(gAb1, rs, As1, wv, lane);
    BAR(); LGKM0();
    __builtin_amdgcn_s_setprio(1); QUAD(1, 1); __builtin_amdgcn_s_setprio(0);
    BAR();

    // ---- ph8: stage b'.A.h1 ; MFMA (m0,n1) ; counted vmcnt (retires a'A +
    //          a'B, needed next ph1; leaves b'A flying).
    if (m2) stage_half(gAb1 + 128*rs, rs, As1 + 128*64, wv, lane);
    BAR();
    __builtin_amdgcn_s_setprio(1); QUAD(0, 1); __builtin_amdgcn_s_setprio(0);
    if (m2) VM4();
    BAR();
  }

  // ---- epilogue: LDS-retranspose coalesced stores ----
  VM0();                                         // safety: all staging retired
  __syncthreads();
  {
    u16* const L = SH;
    const int LROW = 272;
    #pragma unroll
    for (int h = 0; h < 2; ++h) {
      if (h == 1) __syncthreads();               // protect L reuse across passes
      if (wm == h) {
        #pragma unroll
        for (int nf = 0; nf < 4; ++nf) {
          const int col_l = wn*64 + nf*16 + r16;
          const float bvs = (MODE == 0) ? 0.f : bias[n0 + col_l];
          #pragma unroll
          for (int mi = 0; mi < 8; ++mi) {
            const int row_l = mi*16 + q4*4;
            #pragma unroll
            for (int r = 0; r < 4; ++r) {
              float v = acc[mi][nf][r];
              if (MODE == 0)      v = clampf(v, -1.f, 1.f);
              else if (MODE == 1) v = clampf(v + bvs, -3.f, 3.f);
              else if (MODE == 2) v = fmaxf(clampf(v + bvs, -2.f, 2.f), 0.f);
              else                v = clampf(v + bvs, -2.f, 2.f);
              L[(row_l + r)*LROW + col_l] = f2bf(v);
            }
          }
        }
      }
      __syncthreads();
      #pragma unroll
      for (int k = 0; k < 8; ++k) {
        const int ch   = wv*512 + k*64 + lane;   // 16B chunk id (0..4095)
        const int row  = ch >> 5;                // 32 chunks per 256-col row
        const int colu = (ch & 31) * 8;          // u16 col
        short8 d = *(const short8*)&L[row*LROW + colu];
        const int rowg = m0 + h*128 + row;
        const int cg   = n0 + colu;
        if (MODE == 0) {
          const unsigned proj = (unsigned)cg >> 9;
          const unsigned hh   = ((unsigned)cg >> 6) & 7u;
          const unsigned dk   = (unsigned)cg & 63u;
          const int b = rowg / 200;
          const int s = rowg - b*200;
          *(short8*)&QKV[(size_t)proj*projStride + (size_t)hh*12800
                         + (size_t)b*102400 + (size_t)s*64 + dk] = d;
        } else {
          const int N = (MODE == 2) ? 1024 : 512;
          *(short8*)&outB[(size_t)rowg*N + cg] = d;
        }
      }
    }
  }
}

// ---------------------------------------------------------------- fused attention
// 8 waves / 512 threads: 2 q-blocks of 128 rows. THIS ROUND: Ps is per-wave
// DOUBLE-buffered (by kt2&1) and both explicit lgkmcnt(0) walls are removed —
// Ps is wave-private (no cross-wave races; K/V/msk read-only after the one
// __syncthreads) so the compiler's own dependency tracking handles the
// write->read ordering, and without the asm "memory" walls it can hoist the
// next stile's K ds_reads / QK^T under the PV cluster (software pipelining).
// LDS 80.96 KB -> still 2 blocks/CU (16 waves).
__global__ __launch_bounds__(512)
void attn_kernel(const u16* __restrict__ Q, const u16* __restrict__ K,
                 const u16* __restrict__ V, const int* __restrict__ iseq,
                 u16* __restrict__ x2b) {
  __shared__ __align__(16) u16 Ks[208*72];
  __shared__ __align__(16) u16 Vs[64*232];
  __shared__ __align__(16) u16 Ps[8][2][16*40];
  __shared__ float msk[208];

  const int tid = threadIdx.x, lane = tid & 63, wv = tid >> 6;
  const unsigned bid = blockIdx.x;
  const int h = bid & 7;
  const int b = bid >> 3;
  const size_t bh = (size_t)b*8 + h;
  const u16* Kg = K + bh*12800;
  const u16* Vg = V + bh*12800;
  const u16* Qg = Q + bh*12800;

  for (int c = tid; c < 3200; c += 512) {       // K -> Ks[key][dk]
    int row = c >> 4, q = c & 15;
    *(ushort4*)&Ks[row*72 + q*4] = *(const ushort4*)&Kg[row*64 + q*4];
  }
  // V -> Vs[dk][s] transpose: wave w owns d-quads {2w, 2w+1}; lanes walk
  // consecutive s -> contiguous u16 LDS stores (no bank conflicts).
  {
    const int quad = wv*2 + (lane >> 5);        // 0..15
    const int sl   = lane & 31;
    #pragma unroll
    for (int it = 0; it < 7; ++it) {
      const int s = sl + it*32;
      if (s < 200) {
        ushort4 v4 = *(const ushort4*)&Vg[s*64 + quad*4];
        Vs[(quad*4+0)*232 + s] = v4.x;
        Vs[(quad*4+1)*232 + s] = v4.y;
        Vs[(quad*4+2)*232 + s] = v4.z;
        Vs[(quad*4+3)*232 + s] = v4.w;
      }
    }
  }
  for (int c = tid; c < 2048; c += 512) {
    int dk = c >> 5, s2 = 200 + (c & 31);
    Vs[dk*232 + s2] = 0;
  }
  for (int t = tid; t < 208; t += 512)
    msk[t] = (t < 200 && iseq[b*200 + t] != 0) ? 1.f : 0.f;
  __syncthreads();

  const int colk = lane & 15;
  const int fk8 = (lane >> 4) * 8;
  const int prow = (lane >> 4) * 4;
  const f32x4 fz = {0.f,0.f,0.f,0.f};

  for (int qb = 0; qb < 2; ++qb) {
    const int qrow = qb*128 + wv*16 + (lane & 15);
    const int qsrc = qrow < 200 ? qrow : 199;
    short8 qa0 = *(const short8*)&Qg[(size_t)qsrc*64 + fk8];
    short8 qa1 = *(const short8*)&Qg[(size_t)qsrc*64 + 32 + fk8];
    f32x4 oacc[4];
    #pragma unroll
    for (int nt = 0; nt < 4; ++nt) oacc[nt] = fz;
    float rs[4] = {0.f,0.f,0.f,0.f};

    for (int kt2 = 0; kt2 < 7; ++kt2) {
      u16* ps = &Ps[wv][kt2 & 1][0];            // per-wave double buffer
      #pragma unroll
      for (int half = 0; half < 2; ++half) {
        const int stile = kt2*2 + half;
        if (stile < 13) {
          const int key = stile*16 + colk;
          short8 kb0 = *(const short8*)&Ks[key*72 + fk8];
          short8 kb1 = *(const short8*)&Ks[key*72 + 32 + fk8];
          f32x4 sc = fz;
          __builtin_amdgcn_s_setprio(1);
          sc = MFMA16(qa0, kb0, sc);
          sc = MFMA16(qa1, kb1, sc);
          __builtin_amdgcn_s_setprio(0);
          const float mk = msk[key];
          #pragma unroll
          for (int r = 0; r < 4; ++r) {
            float p = __expf(clampf(sc[r]*2.5f, -3.f, 3.f)) * mk;
            rs[r] += p;
            ps[(prow + r)*40 + half*16 + colk] = f2bf(p);
          }
        } else {
          #pragma unroll
          for (int r = 0; r < 4; ++r)
            ps[(prow + r)*40 + half*16 + colk] = 0;
        }
      }
      short8 pa = *(const short8*)&ps[(lane & 15)*40 + fk8];
      const int kb32 = kt2*32;
      __builtin_amdgcn_s_setprio(1);
      #pragma unroll
      for (int nt = 0; nt < 4; ++nt) {
        short8 vb = *(const short8*)&Vs[(nt*16 + colk)*232 + kb32 + fk8];
        oacc[nt] = MFMA16(pa, vb, oacc[nt]);
      }
      __builtin_amdgcn_s_setprio(0);
    }

    #pragma unroll
    for (int m = 1; m <= 8; m <<= 1)
      #pragma unroll
      for (int r = 0; r < 4; ++r) rs[r] += __shfl_xor(rs[r], m);

    const int srow = qb*128 + wv*16 + prow;
    #pragma unroll
    for (int r = 0; r < 4; ++r) {
      const int s = srow + r;
      if (s < 200) {
        const float inv = rs[r] > 0.f ? 1.f/rs[r] : 0.f;
        const size_t base = ((size_t)b*200 + s)*512 + h*64;
        #pragma unroll
        for (int nt = 0; nt < 4; ++nt)
          x2b[base + nt*16 + colk] = f2bf(oacc[nt][r] * inv);
      }
    }
  }
}

// ---------------------------------------------------------------- LN1 (double): xn = LN(x + LN(x+x2)); x from xb (bf16)
__global__ __launch_bounds__(256)
void ln1_kernel(const u16* __restrict__ xb, const u16* __restrict__ x2b,
                const float* __restrict__ g, const float* __restrict__ bb,
                u16* __restrict__ xnb) {
  const int lane = threadIdx.x & 63, wv = threadIdx.x >> 6;
  const size_t t = (size_t)blockIdx.x*4 + wv;
  const int c0 = lane*4, c1 = 256 + lane*4;
  ushort4 xa = *(const ushort4*)&xb[t*512 + c0];
  ushort4 xc = *(const ushort4*)&xb[t*512 + c1];
  ushort4 ha = *(const ushort4*)&x2b[t*512 + c0];
  ushort4 hc = *(const ushort4*)&x2b[t*512 + c1];
  float xv[8] = {bf2f(xa.x),bf2f(xa.y),bf2f(xa.z),bf2f(xa.w),
                 bf2f(xc.x),bf2f(xc.y),bf2f(xc.z),bf2f(xc.w)};
  float tv[8] = {xv[0]+bf2f(ha.x), xv[1]+bf2f(ha.y), xv[2]+bf2f(ha.z), xv[3]+bf2f(ha.w),
                 xv[4]+bf2f(hc.x), xv[5]+bf2f(hc.y), xv[6]+bf2f(hc.z), xv[7]+bf2f(hc.w)};
  float s1 = 0.f, s2 = 0.f;
  #pragma unroll
  for (int i = 0; i < 8; ++i) { s1 += tv[i]; s2 += tv[i]*tv[i]; }
  #pragma unroll
  for (int m = 1; m <= 32; m <<= 1) { s1 += __shfl_xor(s1, m); s2 += __shfl_xor(s2, m); }
  float mean = s1*(1.f/512.f);
  float inv = 1.f/sqrtf(s2*(1.f/512.f) - mean*mean + 1e-6f);
  float4 ga = *(const float4*)(g + c0), gc = *(const float4*)(g + c1);
  float4 ba = *(const float4*)(bb + c0), bc = *(const float4*)(bb + c1);
  float gv[8] = {ga.x,ga.y,ga.z,ga.w, gc.x,gc.y,gc.z,gc.w};
  float bv[8] = {ba.x,ba.y,ba.z,ba.w, bc.x,bc.y,bc.z,bc.w};
  float uv[8]; float s3 = 0.f, s4 = 0.f;
  #pragma unroll
  for (int i = 0; i < 8; ++i) {
    float sa = (tv[i]-mean)*inv*gv[i] + bv[i];
    uv[i] = xv[i] + sa;
    s3 += uv[i]; s4 += uv[i]*uv[i];
  }
  #pragma unroll
  for (int m = 1; m <= 32; m <<= 1) { s3 += __shfl_xor(s3, m); s4 += __shfl_xor(s4, m); }
  float mean2 = s3*(1.f/512.f);
  float inv2 = 1.f/sqrtf(s4*(1.f/512.f) - mean2*mean2 + 1e-6f);
  ushort4 o0, o1;
  o0.x = f2bf((uv[0]-mean2)*inv2*gv[0] + bv[0]);
  o0.y = f2bf((uv[1]-mean2)*inv2*gv[1] + bv[1]);
  o0.z = f2bf((uv[2]-mean2)*inv2*gv[2] + bv[2]);
  o0.w = f2bf((uv[3]-mean2)*inv2*gv[3] + bv[3]);
  o1.x = f2bf((uv[4]-mean2)*inv2*gv[4] + bv[4]);
  o1.y = f2bf((uv[5]-mean2)*inv2*gv[5] + bv[5]);
  o1.z = f2bf((uv[6]-mean2)*inv2*gv[6] + bv[6]);
  o1.w = f2bf((uv[7]-mean2)*inv2*gv[7] + bv[7]);
  *(ushort4*)&xnb[t*512 + c0] = o0;
  *(ushort4*)&xnb[t*512 + c1] = o1;
}

// ---------------------------------------------------------------- LN2 (double) + masked partials — barrier-free
__global__ __launch_bounds__(256)
void ln2_kernel(const u16* __restrict__ xnb, const u16* __restrict__ f2b,
                const float* __restrict__ g, const float* __restrict__ bb,
                const int* __restrict__ iseq, float* __restrict__ seq_acc) {
  const int tid = threadIdx.x, lane = tid & 63, wv = tid >> 6;
  const int q = blockIdx.x, bl = blockIdx.y;
  const int c8 = lane*8;
  float gv[8], bv[8];
  *(float4*)&gv[0] = *(const float4*)(g + c8);
  *(float4*)&gv[4] = *(const float4*)(g + c8 + 4);
  *(float4*)&bv[0] = *(const float4*)(bb + c8);
  *(float4*)&bv[4] = *(const float4*)(bb + c8 + 4);
  float acc[8] = {};
  for (int i = wv; i < 50; i += 4) {
    const int s = q*50 + i;
    const size_t row = (size_t)bl*200 + s;
    short8 xh = *(const short8*)&xnb[row*512 + c8];
    short8 yh = *(const short8*)&f2b[row*512 + c8];
    float xv[8], tv[8];
    #pragma unroll
    for (int j = 0; j < 8; ++j) {
      xv[j] = bf2f((u16)xh[j]);
      tv[j] = xv[j] + bf2f((u16)yh[j]);
    }
    float s1 = 0.f, s2 = 0.f;
    #pragma unroll
    for (int j = 0; j < 8; ++j) { s1 += tv[j]; s2 += tv[j]*tv[j]; }
    #pragma unroll
    for (int m = 1; m <= 32; m <<= 1) { s1 += __shfl_xor(s1,m); s2 += __shfl_xor(s2,m); }
    float mean = s1*(1.f/512.f);
    float inv = 1.f/sqrtf(s2*(1.f/512.f) - mean*mean + 1e-6f);
    float uv[8]; float s3 = 0.f, s4 = 0.f;
    #pragma unroll
    for (int j = 0; j < 8; ++j) {
      uv[j] = xv[j] + (tv[j]-mean)*inv*gv[j] + bv[j];
      s3 += uv[j]; s4 += uv[j]*uv[j];
    }
    #pragma unroll
    for (int m = 1; m <= 32; m <<= 1) { s3 += __shfl_xor(s3,m); s4 += __shfl_xor(s4,m); }
    float mean2 = s3*(1.f/512.f);
    float inv2 = 1.f/sqrtf(s4*(1.f/512.f) - mean2*mean2 + 1e-6f);
    if (iseq[row] != 0) {
      #pragma unroll
      for (int j = 0; j < 8; ++j)
        acc[j] += clampf((uv[j]-mean2)*inv2*gv[j] + bv[j], -5.f, 5.f);
    }
  }
  float* dst = &seq_acc[(((size_t)bl*4 + q)*4 + wv)*512 + c8];
  *(float4*)&dst[0] = *(float4*)&acc[0];
  *(float4*)&dst[4] = *(float4*)&acc[4];
}

// ---------------------------------------------------------------- assemble user vector u (512 x 1152)
__global__ __launch_bounds__(256)
void build_u_kernel(const float* __restrict__ seq_acc, const float* __restrict__ cnt,
                    const float* __restrict__ uac, const float* __restrict__ uti,
                    const int* __restrict__ age, const int* __restrict__ gen,
                    const int* __restrict__ cms,
                    const float* __restrict__ age_tab, const float* __restrict__ gen_tab,
                    const float* __restrict__ cms_tab,
                    const float* __restrict__ ctr_w, const float* __restrict__ ctr_b,
                    const float* __restrict__ ti_w, const float* __restrict__ ti_b,
                    float* __restrict__ u) {
  const int b = blockIdx.x;
  for (int j = threadIdx.x; j < 1152; j += 256) {
    float v;
    if (j < 512) {
      float ssum = 0.f;
      #pragma unroll
      for (int p = 0; p < 16; ++p) ssum += seq_acc[((size_t)b*16 + p)*512 + j];
      v = clampf(ssum / (cnt[b] + 1e-8f), -5.f, 5.f);
    }
    else if (j < 640)  { int e = j-512;  v = uac[b]*ctr_w[e] + ctr_b[e]; }
    else if (j < 768)  { int e = j-640;  v = uti[b]*ti_w[e] + ti_b[e]; }
    else if (j < 896)  { int e = j-768;  v = age_tab[age[b]*128 + e]; }
    else if (j < 1024) { int e = j-896;  v = gen_tab[gen[b]*128 + e]; }
    else               { int e = j-1024; v = cms_tab[cms[b]*128 + e]; }
    u[(size_t)b*1152 + j] = v;
  }
}

// ---------------------------------------------------------------- mlp1
__global__ __launch_bounds__(256)
void mlp1_kernel(const float* __restrict__ u, const float* __restrict__ w,
                 const float* __restrict__ bias, float* __restrict__ h1) {
  __shared__ __align__(16) float As[64][36];
  __shared__ __align__(16) float Wt[32][68];
  const int tid = threadIdx.x;
  const int m0 = blockIdx.x*64, n0 = blockIdx.y*64;
  const int tm = tid >> 4, tn = tid & 15;
  float acc[4][4] = {};
  for (int k0 = 0; k0 < 1152; k0 += 32) {
    for (int c = tid; c < 512; c += 256) {
      int row = c >> 3, q = c & 7;
      *(float4*)&As[row][q*4] = *(const float4*)&u[(size_t)(m0+row)*1152 + k0 + q*4];
      float4 wv4 = *(const float4*)&w[(size_t)(n0+row)*1152 + k0 + q*4];
      Wt[q*4+0][row] = wv4.x; Wt[q*4+1][row] = wv4.y;
      Wt[q*4+2][row] = wv4.z; Wt[q*4+3][row] = wv4.w;
    }
    __syncthreads();
    #pragma unroll
    for (int kk = 0; kk < 32; ++kk) {
      float av[4], bw[4];
      #pragma unroll
      for (int i = 0; i < 4; ++i) av[i] = As[tm*4+i][kk];
      #pragma unroll
      for (int j = 0; j < 4; ++j) bw[j] = Wt[kk][tn*4+j];
      #pragma unroll
      for (int i = 0; i < 4; ++i)
        #pragma unroll
        for (int j = 0; j < 4; ++j) acc[i][j] += av[i]*bw[j];
    }
    __syncthreads();
  }
  #pragma unroll
  for (int i = 0; i < 4; ++i)
    #pragma unroll
    for (int j = 0; j < 4; ++j) {
      int n = n0 + tn*4 + j;
      h1[(size_t)(m0 + tm*4 + i)*1024 + n] = fmaxf(acc[i][j] + bias[n], 0.f);
    }
}

// ---------------------------------------------------------------- mlp2
__global__ __launch_bounds__(256)
void mlp2_kernel(const float* __restrict__ h1, const float* __restrict__ w,
                 const float* __restrict__ bias, float* __restrict__ out) {
  const int tid = threadIdx.x;
  const int m = blockIdx.x*4 + (tid >> 6);
  const int n = tid & 63;
  const float4* hr = (const float4*)(h1 + (size_t)m*1024);
  const float4* wr = (const float4*)(w + (size_t)n*1024);
  float acc = 0.f;
  for (int k4 = 0; k4 < 256; ++k4) {
    float4 a = hr[k4], bw = wr[k4];
    acc += a.x*bw.x + a.y*bw.y + a.z*bw.z + a.w*bw.w;
  }
  out[(size_t)m*64 + n] = acc + bias[n];
}

// ================================================================ launch
extern "C" void kernel_launch(void* const* d_in, const int* in_sizes, int n_in,
                              void* d_out, int out_size, void* d_ws, size_t ws_size,
                              hipStream_t stream) {
  (void)in_sizes; (void)n_in; (void)out_size;
  const int*   item_seq   = (const int*)d_in[0];
  const float* uac        = (const float*)d_in[1];
  const float* uti        = (const float*)d_in[2];
  const int*   age        = (const int*)d_in[3];
  const int*   gen        = (const int*)d_in[4];
  const int*   cms        = (const int*)d_in[5];
  const float* emb        = (const float*)d_in[6];
  const float* in_proj_w  = (const float*)d_in[7];
  const float* out_proj_w = (const float*)d_in[8];
  const float* out_proj_b = (const float*)d_in[9];
  const float* ln1_g = (const float*)d_in[10];
  const float* ln1_b = (const float*)d_in[11];
  const float* ln2_g = (const float*)d_in[12];
  const float* ln2_b = (const float*)d_in[13];
  const float* lin1_w = (const float*)d_in[14];
  const float* lin1_b = (const float*)d_in[15];
  const float* lin2_w = (const float*)d_in[16];
  const float* lin2_b = (const float*)d_in[17];
  const float* age_tab = (const float*)d_in[18];
  const float* gen_tab = (const float*)d_in[19];
  const float* cms_tab = (const float*)d_in[20];
  const float* ctr_w = (const float*)d_in[21];
  const float* ctr_b = (const float*)d_in[22];
  const float* ti_w  = (const float*)d_in[23];
  const float* ti_b  = (const float*)d_in[24];
  const float* mlp1_w = (const float*)d_in[25];
  const float* mlp1_b = (const float*)d_in[26];
  const float* mlp2_w = (const float*)d_in[27];
  const float* mlp2_b = (const float*)d_in[28];

  // ---- adaptive chunking: 5 regions of CB*200*512*2 B each + tail ----
  const long long TAILB = 25430016LL;
  int CB = 32;
  if      ((long long)ws_size >= 512LL*1024000 + TAILB) CB = 512;  // 549.7 MB (ws ~819 MB)
  else if ((long long)ws_size >= 128LL*1024000 + TAILB) CB = 128;
  else if ((long long)ws_size >=  64LL*1024000 + TAILB) CB = 64;
  const long long R = (long long)CB * 204800;

  char* ws = (char*)d_ws;
  u16* xb   = (u16*)(ws);            // region 0: embed bf16 (live through ln1)
  u16* x2b  = (u16*)(ws + R);        // region 1: attn out
  u16* Qb   = (u16*)(ws + 2*R);      // region 2: Q; later x2o
  u16* Kb   = (u16*)(ws + 3*R);      // region 3: K; later xnb
  u16* Vrb  = (u16*)(ws + 4*R);      // region 4: V; later f2b
  u16* x2o  = Qb;
  u16* xnb  = Kb;
  u16* f2b  = Vrb;
  u16* hbuf = (u16*)(ws);            // regions 0-1 (xb,x2b dead after ln1)
  char* tail = ws + 5*R;
  float* seq_acc = (float*)(tail);              // 16,777,216  [B][16][512]
  float* cnt     = (float*)(tail + 16777216);   // 2,048
  float* u       = (float*)(tail + 16779264);   // 2,359,296
  float* h1      = (float*)(tail + 19138560);   // 2,097,152
  u16*   wqkv    = (u16*)(tail + 21235712);     // 1,572,864
  u16*   wout    = (u16*)(tail + 22808576);     // 524,288
  u16*   wl1     = (u16*)(tail + 23332864);     // 1,048,576
  u16*   wl2     = (u16*)(tail + 24381440);     // 1,048,576 -> 25,430,016

  cvt_all_kernel<<<2048, 256, 0, stream>>>(in_proj_w, wqkv, 1536*512,
                                           out_proj_w, wout, 512*512,
                                           lin1_w, wl1, 1024*512,
                                           lin2_w, wl2, 512*1024);
  cnt_kernel<<<512, 256, 0, stream>>>(item_seq, cnt);

  const int nch = 512 / CB;
  const int Mc  = CB * 200;
  const int Mt  = Mc / 256;                    // 256-row tiles
  const int swz = (Mt % 8 == 0) ? 1 : 0;
  const long long projStride = (long long)CB * 102400;
  for (int ch = 0; ch < nch; ++ch) {
    const int* iseq = item_seq + (size_t)ch*CB*200;
    embed_kernel<<<Mc/2, 256, 0, stream>>>(iseq, emb, xb);
    gemm_bt<0><<<Mt*6, 512, 0, stream>>>(xb, wqkv, nullptr, 512, 6, swz,
                                         nullptr, Qb, projStride);
    attn_kernel<<<CB*8, 512, 0, stream>>>(Qb, Kb, Vrb, iseq, x2b);
    gemm_bt<1><<<Mt*2, 512, 0, stream>>>(x2b, wout, out_proj_b, 512, 2, swz,
                                         x2o, nullptr, 0);
    ln1_kernel<<<Mc/4, 256, 0, stream>>>(xb, x2o, ln1_g, ln1_b, xnb);
    gemm_bt<2><<<Mt*4, 512, 0, stream>>>(xnb, wl1, lin1_b, 512, 4, swz,
                                         hbuf, nullptr, 0);
    gemm_bt<3><<<Mt*2, 512, 0, stream>>>(hbuf, wl2, lin2_b, 1024, 2, swz,
                                         f2b, nullptr, 0);
    ln2_kernel<<<dim3(4, CB), 256, 0, stream>>>(xnb, f2b, ln2_g, ln2_b, iseq,
                                                seq_acc + (size_t)ch*CB*8192);
  }

  build_u_kernel<<<512, 256, 0, stream>>>(seq_acc, cnt, uac, uti, age, gen, cms,
                                          age_tab, gen_tab, cms_tab,
                                          ctr_w, ctr_b, ti_w, ti_b, u);
  mlp1_kernel<<<dim3(8, 16), 256, 0, stream>>>(u, mlp1_w, mlp1_b, h1);
  mlp2_kernel<<<128, 256, 0, stream>>>(h1, mlp2_w, mlp2_b, (float*)d_out);
}